// Round 14
// baseline (1317.846 us; speedup 1.0000x reference)
//
#include <hip/hip_runtime.h>
#include <hip/hip_bf16.h>
#include <math.h>

namespace {

constexpr int NU   = 50000;
constexpr int NI   = 30000;
constexpr int D    = 128;
constexpr int EUG  = 2000000;
constexpr int EAND = 1000000;
constexpr int EOR  = 1000000;
constexpr int HNB  = 16;     // chunks per (array,window) unit
constexpr int HW   = 16000;  // max node window (64 KB LDS)

// ---- bf16 helpers ----
__device__ inline float bf_lo(unsigned v) { union { unsigned u; float f; } x{v << 16}; return x.f; }
__device__ inline float bf_hi(unsigned v) { union { unsigned u; float f; } x{v & 0xffff0000u}; return x.f; }
__device__ inline unsigned short f2bf(float f) {
  union { float f; unsigned u; } x{f};
  unsigned r = x.u + 0x7fffu + ((x.u >> 16) & 1u);
  return (unsigned short)(r >> 16);
}
__device__ inline unsigned pack2bf(float a, float b) {
  return (unsigned)f2bf(a) | ((unsigned)f2bf(b) << 16);
}

// ---------- histograms: per-chunk counts, direct stores (no global atomics) + bf16 cvt ----------
struct HistoUnit { const int* idx; int* cntc; int E; int R; int wbeg; int wend; };
struct HistoAll {
  HistoUnit u[22];
  int blkbase[23];
  int nunits;
  int nhisto;
  const float* a; unsigned* ah; long n2a;
  const float* b; unsigned* bh; long n2b;
};
__global__ __launch_bounds__(1024) void histo_cvt_k(HistoAll H) {
  __shared__ int h[HW];
  int gb = (int)blockIdx.x;
  if (gb >= H.nhisto) {
    long nb = (long)gridDim.x - H.nhisto;
    long total = H.n2a + H.n2b;
    for (long t = (long)(gb - H.nhisto) * 1024 + threadIdx.x; t < total; t += nb * 1024) {
      if (t < H.n2a) {
        float2 v = ((const float2*)H.a)[t];
        H.ah[t] = pack2bf(v.x, v.y);
      } else {
        long u = t - H.n2a;
        float2 v = ((const float2*)H.b)[u];
        H.bh[u] = pack2bf(v.x, v.y);
      }
    }
    return;
  }
  int unit = 0;
#pragma unroll
  for (int i = 1; i < 22; ++i) if (i < H.nunits && gb >= H.blkbase[i]) unit = i;
  HistoUnit U = H.u[unit];
  const int W = U.wend - U.wbeg;
  for (int i = threadIdx.x; i < W; i += 1024) h[i] = 0;
  __syncthreads();
  int chunk = gb - H.blkbase[unit];
  long b = (long)U.E * chunk / HNB;
  long e = (long)U.E * (chunk + 1) / HNB;
  const int* __restrict__ idx = U.idx;
  for (long j = b + threadIdx.x; j < e; j += 1024) {
    int v = idx[j] - U.wbeg;
    if ((unsigned)v < (unsigned)W) atomicAdd(&h[v], 1);
  }
  __syncthreads();
  int* __restrict__ dstc = U.cntc + (size_t)chunk * U.R + U.wbeg;
  for (int i = threadIdx.x; i < W; i += 1024) dstc[i] = h[i];
}

// ---------- per-node totals + norms (coalesced: 1 thread / node) ----------
struct RedAll {
  const int* cb[10];
  int rr[10];
  int nb[11];
  int* cnt_all;
  float* inv_all;
  int ncnt;
};
__global__ __launch_bounds__(256) void reduce_norms_k(RedAll S) {
  int t = (int)blockIdx.x * 256 + (int)threadIdx.x;
  if (t >= S.ncnt) return;
  int a = 0;
#pragma unroll
  for (int i = 1; i < 10; ++i) if (t >= S.nb[i]) a = i;
  int n = t - S.nb[a];
  const int* __restrict__ cb = S.cb[a];
  int R = S.rr[a];
  int sum = 0;
#pragma unroll
  for (int c = 0; c < HNB; ++c) sum += cb[(size_t)c * R + n];
  S.cnt_all[t] = sum;
  S.inv_all[t] = rsqrtf((float)max(sum, 1));
}

// ---------- 6-block exclusive scan over per-node totals ----------
struct ScanSeg { const int* cnt; int* off; int n; };
struct ScanAll { ScanSeg s[6]; };
__global__ __launch_bounds__(1024) void exscan_k(ScanAll S) {
  ScanSeg sg = S.s[blockIdx.x];
  __shared__ int ts[1024];
  const int t = threadIdx.x;
  const int per = (sg.n + 1023) >> 10;
  const int b = min(t * per, sg.n);
  const int e = min(b + per, sg.n);
  int s = 0;
  for (int i = b; i < e; ++i) s += sg.cnt[i];
  ts[t] = s;
  __syncthreads();
  for (int d = 1; d < 1024; d <<= 1) {
    int v = (t >= d) ? ts[t - d] : 0;
    __syncthreads();
    ts[t] += v;
    __syncthreads();
  }
  if (t == 1023) sg.off[sg.n] = ts[1023];
  int run = (t == 0) ? 0 : ts[t - 1];
  for (int i = b; i < e; ++i) { sg.off[i] = run; run += sg.cnt[i]; }
}

// ---------- per-chunk cursor bases (coalesced: 1 thread / node) ----------
struct CoffAll {
  const int* cntc[6];
  const int* off[6];
  int* coff[6];
  int n[6];
  int base[7];
};
__global__ __launch_bounds__(256) void coffs_k(CoffAll S) {
  int t = (int)blockIdx.x * 256 + (int)threadIdx.x;
  if (t >= S.base[6]) return;
  int seg = 0;
#pragma unroll
  for (int i = 1; i < 6; ++i) if (t >= S.base[i]) seg = i;
  int n = t - S.base[seg];
  int R = S.n[seg];
  const int* __restrict__ cc = S.cntc[seg];
  int* __restrict__ co = S.coff[seg];
  int run = S.off[seg][n];
#pragma unroll
  for (int c = 0; c < HNB; ++c) {
    co[(size_t)c * R + n] = run;
    run += cc[(size_t)c * R + n];
  }
}

// ---------- atomic-free CSR fill with XCD-chunked swizzle ----------
struct FillUnit {
  const int* dst; const int* src; const float* invS; const int* coff;
  unsigned* meta; int iswt; int E; int R; int wbeg; int wend;
};
struct FillAll {
  FillUnit u[14];
  int blkbase[15];
  int nunits;
  int nblk;
  int n8;
  const float* wn0;
  const float* we0;
};
__global__ __launch_bounds__(1024) void fill_k(FillAll F) {
  __shared__ int cur[HW];
  int b = (int)blockIdx.x;
  int gb = (b & 7) * F.n8 + (b >> 3);   // XCD-chunked
  if (gb >= F.nblk) return;
  int unit = 0;
#pragma unroll
  for (int i = 1; i < 14; ++i) if (i < F.nunits && gb >= F.blkbase[i]) unit = i;
  FillUnit U = F.u[unit];
  const int W = U.wend - U.wbeg;
  int chunk = gb - F.blkbase[unit];
  const int* __restrict__ coff = U.coff + (size_t)chunk * U.R + U.wbeg;
  for (int i = threadIdx.x; i < W; i += 1024) cur[i] = coff[i];
  __syncthreads();
  long bb = (long)U.E * chunk / HNB;
  long ee = (long)U.E * (chunk + 1) / HNB;
  const int* __restrict__ dst = U.dst;
  const int* __restrict__ src = U.src;
  const float* __restrict__ invS = U.invS;
  for (long j = bb + threadIdx.x; j < ee; j += 1024) {
    int dn = dst[j];
    int v = dn - U.wbeg;
    if ((unsigned)v < (unsigned)W) {
      int sn = src[j];
      float w = invS[sn];
      if (U.iswt) w *= F.wn0[sn] * F.we0[j];
      int pos = atomicAdd(&cur[v], 1);
      U.meta[pos] = ((unsigned)f2bf(w) << 16) | (unsigned)sn;
    }
  }
}

// ---------- multi-job pull aggregation: half-wave edge pairing ----------
// One wave per dst row; lanes 0-31 process even edges, 32-63 odd edges.
// Row read = uint2 (8B) x 32 lanes = 256 B -> 1 VMEM per 2 edges.
struct GJob {
  const unsigned* x; const int* roff; const unsigned* meta;
  const float* invD; unsigned* out_h; float* out_f; int rbeg;
};
struct GJobs { GJob j[6]; int total; int xbeg[9]; };

__global__ __launch_bounds__(256) void gather_multi_k(GJobs J) {
  int b = (int)blockIdx.x;
  int xcd = b & 7;
  int vb = J.xbeg[xcd] + (b >> 3);
  if (vb >= J.xbeg[xcd + 1]) return;
  int wid = (vb << 2) | ((int)threadIdx.x >> 6);
  if (wid >= J.total) return;
  GJob jb = J.j[0];
#pragma unroll
  for (int i = 1; i < 6; ++i) if (wid >= J.j[i].rbeg) jb = J.j[i];
  int row = wid - jb.rbeg;
  int lane = (int)threadIdx.x & 63;
  int hf = lane >> 5;          // which edge of the pair
  int l32 = lane & 31;
  int lo = __builtin_amdgcn_readfirstlane(jb.roff[row]);
  int hi = __builtin_amdgcn_readfirstlane(jb.roff[row + 1]);
  const uint2* __restrict__ x2 = (const uint2*)jb.x;
  const unsigned* __restrict__ mt = jb.meta;
  float a0 = 0.f, a1 = 0.f, a2 = 0.f, a3 = 0.f;
  int j = lo;
  for (; j + 7 < hi; j += 8) {
    unsigned mm[8];
#pragma unroll
    for (int k = 0; k < 8; ++k) mm[k] = mt[j + k];
#pragma unroll
    for (int k = 0; k < 8; k += 2) {
      unsigned m = hf ? mm[k + 1] : mm[k];
      int s = (int)(m & 0xffffu);
      float w = bf_hi(m);
      uint2 r = x2[(size_t)s * 32 + l32];
      a0 = fmaf(w, bf_lo(r.x), a0);
      a1 = fmaf(w, bf_hi(r.x), a1);
      a2 = fmaf(w, bf_lo(r.y), a2);
      a3 = fmaf(w, bf_hi(r.y), a3);
    }
  }
  for (; j < hi; j += 2) {
    unsigned m0 = mt[j];
    unsigned m1 = (j + 1 < hi) ? mt[j + 1] : 0u;   // bf16 weight 0 -> no-op edge
    unsigned m = hf ? m1 : m0;
    int s = (int)(m & 0xffffu);
    float w = bf_hi(m);
    uint2 r = x2[(size_t)s * 32 + l32];
    a0 = fmaf(w, bf_lo(r.x), a0);
    a1 = fmaf(w, bf_hi(r.x), a1);
    a2 = fmaf(w, bf_lo(r.y), a2);
    a3 = fmaf(w, bf_hi(r.y), a3);
  }
  // merge the two halves (same channels, disjoint edge subsets)
  a0 += __shfl_xor(a0, 32);
  a1 += __shfl_xor(a1, 32);
  a2 += __shfl_xor(a2, 32);
  a3 += __shfl_xor(a3, 32);
  if (hf == 0) {
    float si = jb.invD[row];
    a0 *= si; a1 *= si; a2 *= si; a3 *= si;
    if (jb.out_f) {
      ((float4*)jb.out_f)[(size_t)row * 32 + l32] = make_float4(a0, a1, a2, a3);
    } else {
      uint2 o;
      o.x = pack2bf(a0, a1);
      o.y = pack2bf(a2, a3);
      ((uint2*)jb.out_h)[(size_t)row * 32 + l32] = o;
    }
  }
}

// ---------- layer attention (verified since r2; bf16 layers) ----------
struct AttnArgs {
  const unsigned* layer[7];
  float coef[7];
};

__device__ inline void osm_upd(float& m, float& den, float& num, float sc, float tv) {
  float nm = fmaxf(m, sc);
  float e0 = __expf(m - nm);
  float e1 = __expf(sc - nm);
  den = den * e0 + e1;
  num = num * e0 + tv * e1;
  m = nm;
}

template <int L>
__global__ __launch_bounds__(256) void attn_k(AttnArgs args,
    const float* __restrict__ W, const float* __restrict__ avec,
    float* __restrict__ out, float out_scale, int beta,
    const unsigned* __restrict__ extra, float escale, int n) {
  __shared__ float4 Ws4[2048];
  __shared__ float xs[32][132];
  const int tid = threadIdx.x;
  const int dt = tid & 15;
  const int grp = tid >> 4;
  const int half = blockIdx.y;
  const int base = blockIdx.x * 32;
  const float4* __restrict__ W4 = (const float4*)W;

  for (int i = tid; i < 2048; i += 256) {
    int k = i >> 4, d = i & 15;
    Ws4[i] = W4[(k << 5) + (half << 4) + d];
  }
  const float4 a4 = ((const float4*)avec)[(half << 4) + dt];
  const float am[4] = {a4.x, a4.y, a4.z, a4.w};

  float m[2][4], den[2][4], num[2][4];
#pragma unroll
  for (int g = 0; g < 2; ++g)
#pragma unroll
    for (int c = 0; c < 4; ++c) { m[g][c] = -3.0e38f; den[g][c] = 0.f; num[g][c] = 0.f; }

#pragma unroll
  for (int l = 0; l < L; ++l) {
    __syncthreads();
    const unsigned* __restrict__ Lh = args.layer[l];
    for (int i = tid; i < 2048; i += 256) {
      int r = i >> 6, c2 = i & 63;
      int node = base + r;
      unsigned v = (node < n) ? Lh[(size_t)node * 64 + c2] : 0u;
      xs[r][(c2 << 1)] = bf_lo(v);
      xs[r][(c2 << 1) + 1] = bf_hi(v);
    }
    __syncthreads();
    float s0[4] = {0.f, 0.f, 0.f, 0.f}, s1[4] = {0.f, 0.f, 0.f, 0.f};
#pragma unroll 4
    for (int k = 0; k < 128; ++k) {
      float4 w = Ws4[(k << 4) + dt];
      float x0 = xs[grp][k];
      float x1 = xs[grp + 16][k];
      s0[0] = fmaf(x0, w.x, s0[0]); s0[1] = fmaf(x0, w.y, s0[1]);
      s0[2] = fmaf(x0, w.z, s0[2]); s0[3] = fmaf(x0, w.w, s0[3]);
      s1[0] = fmaf(x1, w.x, s1[0]); s1[1] = fmaf(x1, w.y, s1[1]);
      s1[2] = fmaf(x1, w.z, s1[2]); s1[3] = fmaf(x1, w.w, s1[3]);
    }
    float c = args.coef[l];
    float4 t0 = *(const float4*)&xs[grp][(half << 6) + (dt << 2)];
    float4 t1 = *(const float4*)&xs[grp + 16][(half << 6) + (dt << 2)];
    const float tv0[4] = {t0.x, t0.y, t0.z, t0.w};
    const float tv1[4] = {t1.x, t1.y, t1.z, t1.w};
#pragma unroll
    for (int ch = 0; ch < 4; ++ch) {
      osm_upd(m[0][ch], den[0][ch], num[0][ch], c * s0[ch] * am[ch], c * tv0[ch]);
      osm_upd(m[1][ch], den[1][ch], num[1][ch], c * s1[ch] * am[ch], c * tv1[ch]);
    }
  }
#pragma unroll
  for (int g = 0; g < 2; ++g) {
    int node = base + grp + g * 16;
    if (node >= n) continue;
    float4 o;
    o.x = num[g][0] / den[g][0];
    o.y = num[g][1] / den[g][1];
    o.z = num[g][2] / den[g][2];
    o.w = num[g][3] / den[g][3];
    size_t oi = (size_t)node * 32 + (half << 4) + dt;
    float4* op = (float4*)out + oi;
    if (beta) {
      float4 pv = *op;
      float ex = 0.f, ey = 0.f, ez = 0.f, ew = 0.f;
      if (extra) {
        uint2 ev = ((const uint2*)extra)[oi];
        ex = bf_lo(ev.x); ey = bf_hi(ev.x); ez = bf_lo(ev.y); ew = bf_hi(ev.y);
      }
      o.x = pv.x + out_scale * o.x + escale * ex;
      o.y = pv.y + out_scale * o.y + escale * ey;
      o.z = pv.z + out_scale * o.z + escale * ez;
      o.w = pv.w + out_scale * o.w + escale * ew;
    } else {
      o.x *= out_scale; o.y *= out_scale; o.z *= out_scale; o.w *= out_scale;
    }
    *op = o;
  }
}

inline dim3 g1(long n) { return dim3((unsigned)((n + 255) / 256)); }

} // namespace

extern "C" void kernel_launch(void* const* d_in, const int* in_sizes, int n_in,
                              void* d_out, int out_size, void* d_ws, size_t ws_size,
                              hipStream_t stream) {
  const int* ug_u = (const int*)d_in[0];
  const int* ug_g = (const int*)d_in[1];
  const int* aS[3] = {(const int*)d_in[2], (const int*)d_in[4], (const int*)d_in[6]};
  const int* aD[3] = {(const int*)d_in[3], (const int*)d_in[5], (const int*)d_in[7]};
  const int* oS = (const int*)d_in[8];
  const int* oD = (const int*)d_in[9];
  const float* ue    = (const float*)d_in[10];
  const float* ie    = (const float*)d_in[11];
  const float* W_and = (const float*)d_in[12];
  const float* a_and = (const float*)d_in[13];
  const float* W_or  = (const float*)d_in[14];
  const float* a_or  = (const float*)d_in[15];
  const float* wedge = (const float*)d_in[16];
  const float* wnode = (const float*)d_in[17];

  // ---- workspace carve-up ----
  char* basep = (char*)d_ws;
  size_t boff_ = 0;
  auto alloc = [&](size_t bytes) -> void* {
    void* r = basep + boff_;
    boff_ += (bytes + 15) & ~(size_t)15;
    return r;
  };

  const int NCNT = NU + 9 * NI;
  const int RR[10] = {NU, NI, NI, NI, NI, NI, NI, NI, NI, NI};
  int* cntc[10];
  for (int i = 0; i < 10; ++i) cntc[i] = (int*)alloc((size_t)HNB * RR[i] * 4);
  int* cnt_all = (int*)alloc((size_t)NCNT * 4);
  float* inv_all = (float*)alloc((size_t)NCNT * 4);
  float* invU = inv_all;
  float* invG = invU + NU;
  float* iAo[3] = {invG + NI, invG + 3 * NI, invG + 5 * NI};
  float* iAi[3] = {invG + 2 * NI, invG + 4 * NI, invG + 6 * NI};
  float* iOo = invG + 7 * NI;
  float* iOi = invG + 8 * NI;
  int* cU_t = cnt_all;
  int* cG_t = cU_t + NU;
  int* cAd_t[3] = {cG_t + 2 * NI, cG_t + 4 * NI, cG_t + 6 * NI};
  int* cOd_t = cG_t + 8 * NI;

  int* oUGu = (int*)alloc((size_t)(NU + 1) * 4);
  int* oUGg = (int*)alloc((size_t)(NI + 1) * 4);
  int* oAnd[3]; for (int i = 0; i < 3; ++i) oAnd[i] = (int*)alloc((size_t)(NI + 1) * 4);
  int* oOr = (int*)alloc((size_t)(NI + 1) * 4);

  const int SR[6] = {NU, NI, NI, NI, NI, NI};
  int* coff[6];
  for (int i = 0; i < 6; ++i) coff[i] = (int*)alloc((size_t)HNB * SR[i] * 4);

  unsigned* mUGu = (unsigned*)alloc((size_t)EUG * 4 + 256);
  unsigned* mUGg = (unsigned*)alloc((size_t)EUG * 4 + 256);
  unsigned* mAnd[3]; for (int i = 0; i < 3; ++i) mAnd[i] = (unsigned*)alloc((size_t)EAND * 4 + 256);
  unsigned* mOr = (unsigned*)alloc((size_t)EOR * 4 + 256);

  unsigned* ieh = (unsigned*)alloc((size_t)NI * 64 * 4);
  unsigned* ueh = (unsigned*)alloc((size_t)NU * 64 * 4);
  unsigned* hu1 = (unsigned*)alloc((size_t)NU * 64 * 4);
  unsigned* hg1 = (unsigned*)alloc((size_t)NI * 64 * 4);
  unsigned* hg2 = (unsigned*)alloc((size_t)NI * 64 * 4);
  unsigned* ab[6]; for (int i = 0; i < 6; ++i) ab[i] = (unsigned*)alloc((size_t)NI * 64 * 4);
  unsigned* ob[3]; for (int i = 0; i < 3; ++i) ob[i] = (unsigned*)alloc((size_t)NI * 64 * 4);

  float* out_hu = (float*)d_out;
  float* out_game = out_hu + (size_t)NU * D;

  // ---- histograms (per-chunk, no atomics) + bf16 conversion ----
  HistoAll H{};
  {
    const int* idxs[10] = {ug_u, ug_g, aS[0], aD[0], aS[1], aD[1], aS[2], aD[2], oS, oD};
    int nu = 0, bb = 0;
    for (int i = 0; i < 10; ++i) {
      int E = (i < 2) ? EUG : ((i < 8) ? EAND : EOR);
      int R = RR[i];
      int npass = (R + HW - 1) / HW;
      int win = (R + npass - 1) / npass;
      for (int p = 0; p < npass; ++p) {
        H.u[nu] = {idxs[i], cntc[i], E, R, p * win, min((p + 1) * win, R)};
        H.blkbase[nu] = bb;
        bb += HNB;
        ++nu;
      }
    }
    H.nunits = nu;
    H.blkbase[nu] = bb;
    H.nhisto = bb;
    H.a = ie; H.ah = ieh; H.n2a = (long)NI * 64;
    H.b = ue; H.bh = ueh; H.n2b = (long)NU * 64;
    int ncvt = 1024;
    histo_cvt_k<<<dim3(bb + ncvt), 1024, 0, stream>>>(H);
  }

  // ---- per-node totals + norms (coalesced) ----
  RedAll RA{};
  {
    int nbase = 0;
    for (int i = 0; i < 10; ++i) { RA.cb[i] = cntc[i]; RA.rr[i] = RR[i]; RA.nb[i] = nbase; nbase += RR[i]; }
    RA.nb[10] = nbase;
    RA.cnt_all = cnt_all; RA.inv_all = inv_all; RA.ncnt = NCNT;
  }
  reduce_norms_k<<<g1(NCNT), 256, 0, stream>>>(RA);

  // ---- 6-block exclusive scans over totals ----
  ScanAll SA{};
  SA.s[0] = {cU_t, oUGu, NU};
  SA.s[1] = {cG_t, oUGg, NI};
  for (int i = 0; i < 3; ++i) SA.s[2 + i] = {cAd_t[i], oAnd[i], NI};
  SA.s[5] = {cOd_t, oOr, NI};
  exscan_k<<<dim3(6), 1024, 0, stream>>>(SA);

  // ---- per-chunk cursor bases (coalesced) ----
  CoffAll CA{};
  {
    const int segArr[6] = {0, 1, 3, 5, 7, 9};
    const int* offs[6] = {oUGu, oUGg, oAnd[0], oAnd[1], oAnd[2], oOr};
    int base = 0;
    for (int i = 0; i < 6; ++i) {
      CA.cntc[i] = cntc[segArr[i]];
      CA.off[i] = offs[i];
      CA.coff[i] = coff[i];
      CA.n[i] = SR[i];
      CA.base[i] = base; base += SR[i];
    }
    CA.base[6] = base;
    coffs_k<<<g1(base), 256, 0, stream>>>(CA);
  }

  // ---- atomic-free CSR fill (XCD-chunked, big/small interleaved) ----
  FillAll F{};
  {
    const int* ds[6] = {ug_u, ug_g, aD[0], aD[1], aD[2], oD};
    const int* ss[6] = {ug_g, ug_u, aS[0], aS[1], aS[2], oS};
    const float* iv[6] = {invG, invU, iAo[0], iAo[1], iAo[2], iOo};
    unsigned* ms[6] = {mUGu, mUGg, mAnd[0], mAnd[1], mAnd[2], mOr};
    int Es[6] = {EUG, EUG, EAND, EAND, EAND, EOR};
    FillUnit big[8], sml[12];
    int nbig = 0, nsml = 0;
    for (int i = 0; i < 6; ++i) {
      int R = SR[i];
      int npass = (R + HW - 1) / HW;
      int win = (R + npass - 1) / npass;
      for (int p = 0; p < npass; ++p) {
        FillUnit u = {ds[i], ss[i], iv[i], coff[i], ms[i], (i == 0) ? 1 : 0,
                      Es[i], R, p * win, min((p + 1) * win, R)};
        if (i < 2) big[nbig++] = u; else sml[nsml++] = u;
      }
    }
    int nu = 0, bb = 0, ib = 0, is = 0;
    while (ib < nbig || is < nsml) {
      if (ib < nbig) { F.u[nu] = big[ib++]; F.blkbase[nu] = bb; bb += HNB; ++nu; }
      if (is < nsml) { F.u[nu] = sml[is++]; F.blkbase[nu] = bb; bb += HNB; ++nu; }
    }
    F.nunits = nu;
    F.blkbase[nu] = bb;
    F.nblk = bb;
    F.n8 = (bb + 7) / 8;
    F.wn0 = wnode; F.we0 = wedge;
    fill_k<<<dim3(F.n8 * 8), 1024, 0, stream>>>(F);
  }

  // ---- gathers (multi-job, edge-balanced XCD chunking) ----
  auto launch_bg = [&](GJob* jobs, const int* rows, const long* edges, int nj) {
    GJobs J{};
    int tot = 0;
    long totE = 0;
    for (int k = 0; k < nj; ++k) {
      J.j[k] = jobs[k];
      J.j[k].rbeg = tot;
      tot += rows[k];
      totE += edges[k];
    }
    for (int k = nj; k < 6; ++k) { J.j[k] = J.j[0]; J.j[k].rbeg = 0x7fffffff; }
    J.total = tot;
    int nblk = (tot + 3) / 4;
    J.xbeg[0] = 0;
    for (int x = 1; x < 8; ++x) {
      double target = (double)totE * x / 8.0;
      double cum = 0.0;
      int widbase = 0, wid = tot;
      for (int k = 0; k < nj; ++k) {
        double je = (double)edges[k];
        if (cum + je >= target) {
          double frac = (target - cum) / je;
          wid = widbase + (int)(frac * rows[k]);
          break;
        }
        cum += je;
        widbase += rows[k];
      }
      int vb = wid >> 2;
      if (vb < J.xbeg[x - 1]) vb = J.xbeg[x - 1];
      if (vb > nblk) vb = nblk;
      J.xbeg[x] = vb;
    }
    J.xbeg[8] = nblk;
    int maxspan = 0;
    for (int x = 0; x < 8; ++x) maxspan = max(maxspan, J.xbeg[x + 1] - J.xbeg[x]);
    gather_multi_k<<<dim3(maxspan * 8), 256, 0, stream>>>(J);
  };

  // G1 (same-table jobs adjacent: five ieh-readers first, ueh-reader last)
  {
    GJob js[6] = {
      {ieh, oUGu, mUGu, invU, hu1, nullptr, 0},
      {ieh, oAnd[0], mAnd[0], iAi[0], ab[0], nullptr, 0},
      {ieh, oAnd[1], mAnd[1], iAi[1], ab[1], nullptr, 0},
      {ieh, oAnd[2], mAnd[2], iAi[2], ab[2], nullptr, 0},
      {ieh, oOr, mOr, iOi, ob[0], nullptr, 0},
      {ueh, oUGg, mUGg, invG, hg1, nullptr, 0},
    };
    const int rows[6] = {NU, NI, NI, NI, NI, NI};
    const long edges[6] = {EUG, EAND, EAND, EAND, EOR, EUG};
    launch_bg(js, rows, edges, 6);
  }
  // G2 (6 distinct tables)
  {
    GJob js[6] = {
      {hg1, oUGu, mUGu, invU, nullptr, out_hu, 0},
      {hu1, oUGg, mUGg, invG, hg2, nullptr, 0},
      {ab[0], oAnd[0], mAnd[0], iAi[0], ab[3], nullptr, 0},
      {ab[1], oAnd[1], mAnd[1], iAi[1], ab[4], nullptr, 0},
      {ab[2], oAnd[2], mAnd[2], iAi[2], ab[5], nullptr, 0},
      {ob[0], oOr, mOr, iOi, ob[1], nullptr, 0},
    };
    const int rows[6] = {NU, NI, NI, NI, NI, NI};
    const long edges[6] = {EUG, EUG, EAND, EAND, EAND, EOR};
    launch_bg(js, rows, edges, 6);
  }
  // G3: ob2<-ob1
  {
    GJob js[1] = {{ob[1], oOr, mOr, iOi, ob[2], nullptr, 0}};
    const int rows[1] = {NI};
    const long edges[1] = {EOR};
    launch_bg(js, rows, edges, 1);
  }

  const float w_or = 80.0f / 82.0f;
  const float w_and = w_or / 80.0f;   // = 1/82
  const float w_self = w_and;

  // ---- layer attention ----
  AttnArgs aa{};
  aa.layer[0] = ieh;
  for (int i = 0; i < 6; ++i) aa.layer[1 + i] = ab[i];
  for (int i = 0; i < 7; ++i) aa.coef[i] = 1.0f;
  attn_k<7><<<dim3((NI + 31) / 32, 2), 256, 0, stream>>>(
      aa, W_and, a_and, out_game, w_and, 0, nullptr, 0.f, NI);

  AttnArgs ao{};
  ao.layer[0] = ieh; ao.layer[1] = ob[0]; ao.layer[2] = ob[1]; ao.layer[3] = ob[2];
  ao.coef[0] = 1.0f; ao.coef[1] = 0.6f; ao.coef[2] = 0.8f; ao.coef[3] = 1.0f;
  attn_k<4><<<dim3((NI + 31) / 32, 2), 256, 0, stream>>>(
      ao, W_or, a_or, out_game, w_or, 1, hg2, w_self, NI);
}

// Round 15
// 1222.211 us; speedup vs baseline: 1.0782x; 1.0782x over previous
//
#include <hip/hip_runtime.h>
#include <hip/hip_bf16.h>
#include <math.h>

namespace {

constexpr int NU   = 50000;
constexpr int NI   = 30000;
constexpr int D    = 128;
constexpr int EUG  = 2000000;
constexpr int EAND = 1000000;
constexpr int EOR  = 1000000;
constexpr int HNB  = 32;     // chunks per (array,window) unit (r14: 16 -> 32 for CU coverage)
constexpr int HW   = 16000;  // max node window (64 KB LDS)

// ---- bf16 helpers ----
__device__ inline float bf_lo(unsigned v) { union { unsigned u; float f; } x{v << 16}; return x.f; }
__device__ inline float bf_hi(unsigned v) { union { unsigned u; float f; } x{v & 0xffff0000u}; return x.f; }
__device__ inline unsigned short f2bf(float f) {
  union { float f; unsigned u; } x{f};
  unsigned r = x.u + 0x7fffu + ((x.u >> 16) & 1u);
  return (unsigned short)(r >> 16);
}
__device__ inline unsigned pack2bf(float a, float b) {
  return (unsigned)f2bf(a) | ((unsigned)f2bf(b) << 16);
}

// ---------- histograms: per-chunk counts, direct stores (no global atomics) + bf16 cvt ----------
struct HistoUnit { const int* idx; int* cntc; int E; int R; int wbeg; int wend; };
struct HistoAll {
  HistoUnit u[22];
  int blkbase[23];
  int nunits;
  int nhisto;
  const float* a; unsigned* ah; long n2a;
  const float* b; unsigned* bh; long n2b;
};
__global__ __launch_bounds__(1024) void histo_cvt_k(HistoAll H) {
  __shared__ int h[HW];
  int gb = (int)blockIdx.x;
  if (gb >= H.nhisto) {
    long nb = (long)gridDim.x - H.nhisto;
    long total = H.n2a + H.n2b;
    for (long t = (long)(gb - H.nhisto) * 1024 + threadIdx.x; t < total; t += nb * 1024) {
      if (t < H.n2a) {
        float2 v = ((const float2*)H.a)[t];
        H.ah[t] = pack2bf(v.x, v.y);
      } else {
        long u = t - H.n2a;
        float2 v = ((const float2*)H.b)[u];
        H.bh[u] = pack2bf(v.x, v.y);
      }
    }
    return;
  }
  int unit = 0;
#pragma unroll
  for (int i = 1; i < 22; ++i) if (i < H.nunits && gb >= H.blkbase[i]) unit = i;
  HistoUnit U = H.u[unit];
  const int W = U.wend - U.wbeg;
  for (int i = threadIdx.x; i < W; i += 1024) h[i] = 0;
  __syncthreads();
  int chunk = gb - H.blkbase[unit];
  long b = (long)U.E * chunk / HNB;
  long e = (long)U.E * (chunk + 1) / HNB;
  const int* __restrict__ idx = U.idx;
  for (long j = b + threadIdx.x; j < e; j += 1024) {
    int v = idx[j] - U.wbeg;
    if ((unsigned)v < (unsigned)W) atomicAdd(&h[v], 1);
  }
  __syncthreads();
  int* __restrict__ dstc = U.cntc + (size_t)chunk * U.R + U.wbeg;
  for (int i = threadIdx.x; i < W; i += 1024) dstc[i] = h[i];
}

// ---------- per-node totals + norms (coalesced: 1 thread / node) ----------
struct RedAll {
  const int* cb[10];
  int rr[10];
  int nb[11];
  int* cnt_all;
  float* inv_all;
  int ncnt;
};
__global__ __launch_bounds__(256) void reduce_norms_k(RedAll S) {
  int t = (int)blockIdx.x * 256 + (int)threadIdx.x;
  if (t >= S.ncnt) return;
  int a = 0;
#pragma unroll
  for (int i = 1; i < 10; ++i) if (t >= S.nb[i]) a = i;
  int n = t - S.nb[a];
  const int* __restrict__ cb = S.cb[a];
  int R = S.rr[a];
  int sum = 0;
#pragma unroll
  for (int c = 0; c < HNB; ++c) sum += cb[(size_t)c * R + n];
  S.cnt_all[t] = sum;
  S.inv_all[t] = rsqrtf((float)max(sum, 1));
}

// ---------- 6-block exclusive scan over per-node totals ----------
struct ScanSeg { const int* cnt; int* off; int n; };
struct ScanAll { ScanSeg s[6]; };
__global__ __launch_bounds__(1024) void exscan_k(ScanAll S) {
  ScanSeg sg = S.s[blockIdx.x];
  __shared__ int ts[1024];
  const int t = threadIdx.x;
  const int per = (sg.n + 1023) >> 10;
  const int b = min(t * per, sg.n);
  const int e = min(b + per, sg.n);
  int s = 0;
  for (int i = b; i < e; ++i) s += sg.cnt[i];
  ts[t] = s;
  __syncthreads();
  for (int d = 1; d < 1024; d <<= 1) {
    int v = (t >= d) ? ts[t - d] : 0;
    __syncthreads();
    ts[t] += v;
    __syncthreads();
  }
  if (t == 1023) sg.off[sg.n] = ts[1023];
  int run = (t == 0) ? 0 : ts[t - 1];
  for (int i = b; i < e; ++i) { sg.off[i] = run; run += sg.cnt[i]; }
}

// ---------- per-chunk cursor bases (coalesced: 1 thread / node) ----------
struct CoffAll {
  const int* cntc[6];
  const int* off[6];
  int* coff[6];
  int n[6];
  int base[7];
};
__global__ __launch_bounds__(256) void coffs_k(CoffAll S) {
  int t = (int)blockIdx.x * 256 + (int)threadIdx.x;
  if (t >= S.base[6]) return;
  int seg = 0;
#pragma unroll
  for (int i = 1; i < 6; ++i) if (t >= S.base[i]) seg = i;
  int n = t - S.base[seg];
  int R = S.n[seg];
  const int* __restrict__ cc = S.cntc[seg];
  int* __restrict__ co = S.coff[seg];
  int run = S.off[seg][n];
#pragma unroll
  for (int c = 0; c < HNB; ++c) {
    co[(size_t)c * R + n] = run;
    run += cc[(size_t)c * R + n];
  }
}

// ---------- atomic-free CSR fill with XCD-chunked swizzle ----------
struct FillUnit {
  const int* dst; const int* src; const float* invS; const int* coff;
  unsigned* meta; int iswt; int E; int R; int wbeg; int wend;
};
struct FillAll {
  FillUnit u[14];
  int blkbase[15];
  int nunits;
  int nblk;
  int n8;
  const float* wn0;
  const float* we0;
};
__global__ __launch_bounds__(1024) void fill_k(FillAll F) {
  __shared__ int cur[HW];
  int b = (int)blockIdx.x;
  int gb = (b & 7) * F.n8 + (b >> 3);   // XCD-chunked
  if (gb >= F.nblk) return;
  int unit = 0;
#pragma unroll
  for (int i = 1; i < 14; ++i) if (i < F.nunits && gb >= F.blkbase[i]) unit = i;
  FillUnit U = F.u[unit];
  const int W = U.wend - U.wbeg;
  int chunk = gb - F.blkbase[unit];
  const int* __restrict__ coff = U.coff + (size_t)chunk * U.R + U.wbeg;
  for (int i = threadIdx.x; i < W; i += 1024) cur[i] = coff[i];
  __syncthreads();
  long bb = (long)U.E * chunk / HNB;
  long ee = (long)U.E * (chunk + 1) / HNB;
  const int* __restrict__ dst = U.dst;
  const int* __restrict__ src = U.src;
  const float* __restrict__ invS = U.invS;
  for (long j = bb + threadIdx.x; j < ee; j += 1024) {
    int dn = dst[j];
    int v = dn - U.wbeg;
    if ((unsigned)v < (unsigned)W) {
      int sn = src[j];
      float w = invS[sn];
      if (U.iswt) w *= F.wn0[sn] * F.we0[j];
      int pos = atomicAdd(&cur[v], 1);
      U.meta[pos] = ((unsigned)f2bf(w) << 16) | (unsigned)sn;
    }
  }
}

// ---------- multi-job pull aggregation (r13-proven form, edge-balanced XCD chunking) ----------
struct GJob {
  const unsigned* x; const int* roff; const unsigned* meta;
  const float* invD; unsigned* out_h; float* out_f; int rbeg;
};
struct GJobs { GJob j[6]; int total; int xbeg[9]; };

__global__ __launch_bounds__(256) void gather_multi_k(GJobs J) {
  int b = (int)blockIdx.x;
  int xcd = b & 7;
  int vb = J.xbeg[xcd] + (b >> 3);
  if (vb >= J.xbeg[xcd + 1]) return;
  int wid = (vb << 2) | ((int)threadIdx.x >> 6);
  if (wid >= J.total) return;
  GJob jb = J.j[0];
#pragma unroll
  for (int i = 1; i < 6; ++i) if (wid >= J.j[i].rbeg) jb = J.j[i];
  int row = wid - jb.rbeg;
  int lane = (int)threadIdx.x & 63;
  int lo = __builtin_amdgcn_readfirstlane(jb.roff[row]);
  int hi = __builtin_amdgcn_readfirstlane(jb.roff[row + 1]);
  const unsigned* __restrict__ x = jb.x;
  const unsigned* __restrict__ mt = jb.meta;
  float ax = 0.f, ay = 0.f;
  int j = lo;
  for (; j + 7 < hi; j += 8) {
    unsigned mm[8];
#pragma unroll
    for (int k = 0; k < 8; ++k) mm[k] = mt[j + k];
#pragma unroll
    for (int k = 0; k < 8; ++k) {
      int s = (int)(mm[k] & 0xffffu);
      float w = bf_hi(mm[k]);
      unsigned r = x[(size_t)s * 64 + lane];
      ax = fmaf(w, bf_lo(r), ax);
      ay = fmaf(w, bf_hi(r), ay);
    }
  }
  for (; j < hi; ++j) {
    unsigned m = mt[j];
    int s = (int)(m & 0xffffu);
    float w = bf_hi(m);
    unsigned r = x[(size_t)s * 64 + lane];
    ax = fmaf(w, bf_lo(r), ax);
    ay = fmaf(w, bf_hi(r), ay);
  }
  float si = jb.invD[row];
  ax *= si; ay *= si;
  size_t oi = (size_t)row * 64 + lane;
  if (jb.out_f) {
    float2 o; o.x = ax; o.y = ay;
    ((float2*)jb.out_f)[oi] = o;
  } else {
    jb.out_h[oi] = pack2bf(ax, ay);
  }
}

// ---------- layer attention (verified since r2; bf16 layers) ----------
struct AttnArgs {
  const unsigned* layer[7];
  float coef[7];
};

__device__ inline void osm_upd(float& m, float& den, float& num, float sc, float tv) {
  float nm = fmaxf(m, sc);
  float e0 = __expf(m - nm);
  float e1 = __expf(sc - nm);
  den = den * e0 + e1;
  num = num * e0 + tv * e1;
  m = nm;
}

template <int L>
__global__ __launch_bounds__(256) void attn_k(AttnArgs args,
    const float* __restrict__ W, const float* __restrict__ avec,
    float* __restrict__ out, float out_scale, int beta,
    const unsigned* __restrict__ extra, float escale, int n) {
  __shared__ float4 Ws4[2048];
  __shared__ float xs[32][132];
  const int tid = threadIdx.x;
  const int dt = tid & 15;
  const int grp = tid >> 4;
  const int half = blockIdx.y;
  const int base = blockIdx.x * 32;
  const float4* __restrict__ W4 = (const float4*)W;

  for (int i = tid; i < 2048; i += 256) {
    int k = i >> 4, d = i & 15;
    Ws4[i] = W4[(k << 5) + (half << 4) + d];
  }
  const float4 a4 = ((const float4*)avec)[(half << 4) + dt];
  const float am[4] = {a4.x, a4.y, a4.z, a4.w};

  float m[2][4], den[2][4], num[2][4];
#pragma unroll
  for (int g = 0; g < 2; ++g)
#pragma unroll
    for (int c = 0; c < 4; ++c) { m[g][c] = -3.0e38f; den[g][c] = 0.f; num[g][c] = 0.f; }

#pragma unroll
  for (int l = 0; l < L; ++l) {
    __syncthreads();
    const unsigned* __restrict__ Lh = args.layer[l];
    for (int i = tid; i < 2048; i += 256) {
      int r = i >> 6, c2 = i & 63;
      int node = base + r;
      unsigned v = (node < n) ? Lh[(size_t)node * 64 + c2] : 0u;
      xs[r][(c2 << 1)] = bf_lo(v);
      xs[r][(c2 << 1) + 1] = bf_hi(v);
    }
    __syncthreads();
    float s0[4] = {0.f, 0.f, 0.f, 0.f}, s1[4] = {0.f, 0.f, 0.f, 0.f};
#pragma unroll 4
    for (int k = 0; k < 128; ++k) {
      float4 w = Ws4[(k << 4) + dt];
      float x0 = xs[grp][k];
      float x1 = xs[grp + 16][k];
      s0[0] = fmaf(x0, w.x, s0[0]); s0[1] = fmaf(x0, w.y, s0[1]);
      s0[2] = fmaf(x0, w.z, s0[2]); s0[3] = fmaf(x0, w.w, s0[3]);
      s1[0] = fmaf(x1, w.x, s1[0]); s1[1] = fmaf(x1, w.y, s1[1]);
      s1[2] = fmaf(x1, w.z, s1[2]); s1[3] = fmaf(x1, w.w, s1[3]);
    }
    float c = args.coef[l];
    float4 t0 = *(const float4*)&xs[grp][(half << 6) + (dt << 2)];
    float4 t1 = *(const float4*)&xs[grp + 16][(half << 6) + (dt << 2)];
    const float tv0[4] = {t0.x, t0.y, t0.z, t0.w};
    const float tv1[4] = {t1.x, t1.y, t1.z, t1.w};
#pragma unroll
    for (int ch = 0; ch < 4; ++ch) {
      osm_upd(m[0][ch], den[0][ch], num[0][ch], c * s0[ch] * am[ch], c * tv0[ch]);
      osm_upd(m[1][ch], den[1][ch], num[1][ch], c * s1[ch] * am[ch], c * tv1[ch]);
    }
  }
#pragma unroll
  for (int g = 0; g < 2; ++g) {
    int node = base + grp + g * 16;
    if (node >= n) continue;
    float4 o;
    o.x = num[g][0] / den[g][0];
    o.y = num[g][1] / den[g][1];
    o.z = num[g][2] / den[g][2];
    o.w = num[g][3] / den[g][3];
    size_t oi = (size_t)node * 32 + (half << 4) + dt;
    float4* op = (float4*)out + oi;
    if (beta) {
      float4 pv = *op;
      float ex = 0.f, ey = 0.f, ez = 0.f, ew = 0.f;
      if (extra) {
        uint2 ev = ((const uint2*)extra)[oi];
        ex = bf_lo(ev.x); ey = bf_hi(ev.x); ez = bf_lo(ev.y); ew = bf_hi(ev.y);
      }
      o.x = pv.x + out_scale * o.x + escale * ex;
      o.y = pv.y + out_scale * o.y + escale * ey;
      o.z = pv.z + out_scale * o.z + escale * ez;
      o.w = pv.w + out_scale * o.w + escale * ew;
    } else {
      o.x *= out_scale; o.y *= out_scale; o.z *= out_scale; o.w *= out_scale;
    }
    *op = o;
  }
}

inline dim3 g1(long n) { return dim3((unsigned)((n + 255) / 256)); }

} // namespace

extern "C" void kernel_launch(void* const* d_in, const int* in_sizes, int n_in,
                              void* d_out, int out_size, void* d_ws, size_t ws_size,
                              hipStream_t stream) {
  const int* ug_u = (const int*)d_in[0];
  const int* ug_g = (const int*)d_in[1];
  const int* aS[3] = {(const int*)d_in[2], (const int*)d_in[4], (const int*)d_in[6]};
  const int* aD[3] = {(const int*)d_in[3], (const int*)d_in[5], (const int*)d_in[7]};
  const int* oS = (const int*)d_in[8];
  const int* oD = (const int*)d_in[9];
  const float* ue    = (const float*)d_in[10];
  const float* ie    = (const float*)d_in[11];
  const float* W_and = (const float*)d_in[12];
  const float* a_and = (const float*)d_in[13];
  const float* W_or  = (const float*)d_in[14];
  const float* a_or  = (const float*)d_in[15];
  const float* wedge = (const float*)d_in[16];
  const float* wnode = (const float*)d_in[17];

  // ---- workspace carve-up ----
  char* basep = (char*)d_ws;
  size_t boff_ = 0;
  auto alloc = [&](size_t bytes) -> void* {
    void* r = basep + boff_;
    boff_ += (bytes + 15) & ~(size_t)15;
    return r;
  };

  const int NCNT = NU + 9 * NI;
  const int RR[10] = {NU, NI, NI, NI, NI, NI, NI, NI, NI, NI};
  int* cntc[10];
  for (int i = 0; i < 10; ++i) cntc[i] = (int*)alloc((size_t)HNB * RR[i] * 4);
  int* cnt_all = (int*)alloc((size_t)NCNT * 4);
  float* inv_all = (float*)alloc((size_t)NCNT * 4);
  float* invU = inv_all;
  float* invG = invU + NU;
  float* iAo[3] = {invG + NI, invG + 3 * NI, invG + 5 * NI};
  float* iAi[3] = {invG + 2 * NI, invG + 4 * NI, invG + 6 * NI};
  float* iOo = invG + 7 * NI;
  float* iOi = invG + 8 * NI;
  int* cU_t = cnt_all;
  int* cG_t = cU_t + NU;
  int* cAd_t[3] = {cG_t + 2 * NI, cG_t + 4 * NI, cG_t + 6 * NI};
  int* cOd_t = cG_t + 8 * NI;

  int* oUGu = (int*)alloc((size_t)(NU + 1) * 4);
  int* oUGg = (int*)alloc((size_t)(NI + 1) * 4);
  int* oAnd[3]; for (int i = 0; i < 3; ++i) oAnd[i] = (int*)alloc((size_t)(NI + 1) * 4);
  int* oOr = (int*)alloc((size_t)(NI + 1) * 4);

  const int SR[6] = {NU, NI, NI, NI, NI, NI};
  int* coff[6];
  for (int i = 0; i < 6; ++i) coff[i] = (int*)alloc((size_t)HNB * SR[i] * 4);

  unsigned* mUGu = (unsigned*)alloc((size_t)EUG * 4 + 256);
  unsigned* mUGg = (unsigned*)alloc((size_t)EUG * 4 + 256);
  unsigned* mAnd[3]; for (int i = 0; i < 3; ++i) mAnd[i] = (unsigned*)alloc((size_t)EAND * 4 + 256);
  unsigned* mOr = (unsigned*)alloc((size_t)EOR * 4 + 256);

  unsigned* ieh = (unsigned*)alloc((size_t)NI * 64 * 4);
  unsigned* ueh = (unsigned*)alloc((size_t)NU * 64 * 4);
  unsigned* hu1 = (unsigned*)alloc((size_t)NU * 64 * 4);
  unsigned* hg1 = (unsigned*)alloc((size_t)NI * 64 * 4);
  unsigned* hg2 = (unsigned*)alloc((size_t)NI * 64 * 4);
  unsigned* ab[6]; for (int i = 0; i < 6; ++i) ab[i] = (unsigned*)alloc((size_t)NI * 64 * 4);
  unsigned* ob[3]; for (int i = 0; i < 3; ++i) ob[i] = (unsigned*)alloc((size_t)NI * 64 * 4);

  float* out_hu = (float*)d_out;
  float* out_game = out_hu + (size_t)NU * D;

  // ---- histograms (per-chunk, no atomics) + bf16 conversion ----
  HistoAll H{};
  {
    const int* idxs[10] = {ug_u, ug_g, aS[0], aD[0], aS[1], aD[1], aS[2], aD[2], oS, oD};
    int nu = 0, bb = 0;
    for (int i = 0; i < 10; ++i) {
      int E = (i < 2) ? EUG : ((i < 8) ? EAND : EOR);
      int R = RR[i];
      int npass = (R + HW - 1) / HW;
      int win = (R + npass - 1) / npass;
      for (int p = 0; p < npass; ++p) {
        H.u[nu] = {idxs[i], cntc[i], E, R, p * win, min((p + 1) * win, R)};
        H.blkbase[nu] = bb;
        bb += HNB;
        ++nu;
      }
    }
    H.nunits = nu;
    H.blkbase[nu] = bb;
    H.nhisto = bb;
    H.a = ie; H.ah = ieh; H.n2a = (long)NI * 64;
    H.b = ue; H.bh = ueh; H.n2b = (long)NU * 64;
    int ncvt = 1024;
    histo_cvt_k<<<dim3(bb + ncvt), 1024, 0, stream>>>(H);
  }

  // ---- per-node totals + norms (coalesced) ----
  RedAll RA{};
  {
    int nbase = 0;
    for (int i = 0; i < 10; ++i) { RA.cb[i] = cntc[i]; RA.rr[i] = RR[i]; RA.nb[i] = nbase; nbase += RR[i]; }
    RA.nb[10] = nbase;
    RA.cnt_all = cnt_all; RA.inv_all = inv_all; RA.ncnt = NCNT;
  }
  reduce_norms_k<<<g1(NCNT), 256, 0, stream>>>(RA);

  // ---- 6-block exclusive scans over totals ----
  ScanAll SA{};
  SA.s[0] = {cU_t, oUGu, NU};
  SA.s[1] = {cG_t, oUGg, NI};
  for (int i = 0; i < 3; ++i) SA.s[2 + i] = {cAd_t[i], oAnd[i], NI};
  SA.s[5] = {cOd_t, oOr, NI};
  exscan_k<<<dim3(6), 1024, 0, stream>>>(SA);

  // ---- per-chunk cursor bases (coalesced) ----
  CoffAll CA{};
  {
    const int segArr[6] = {0, 1, 3, 5, 7, 9};
    const int* offs[6] = {oUGu, oUGg, oAnd[0], oAnd[1], oAnd[2], oOr};
    int base = 0;
    for (int i = 0; i < 6; ++i) {
      CA.cntc[i] = cntc[segArr[i]];
      CA.off[i] = offs[i];
      CA.coff[i] = coff[i];
      CA.n[i] = SR[i];
      CA.base[i] = base; base += SR[i];
    }
    CA.base[6] = base;
    coffs_k<<<g1(base), 256, 0, stream>>>(CA);
  }

  // ---- atomic-free CSR fill (XCD-chunked, big/small interleaved) ----
  FillAll F{};
  {
    const int* ds[6] = {ug_u, ug_g, aD[0], aD[1], aD[2], oD};
    const int* ss[6] = {ug_g, ug_u, aS[0], aS[1], aS[2], oS};
    const float* iv[6] = {invG, invU, iAo[0], iAo[1], iAo[2], iOo};
    unsigned* ms[6] = {mUGu, mUGg, mAnd[0], mAnd[1], mAnd[2], mOr};
    int Es[6] = {EUG, EUG, EAND, EAND, EAND, EOR};
    FillUnit big[8], sml[12];
    int nbig = 0, nsml = 0;
    for (int i = 0; i < 6; ++i) {
      int R = SR[i];
      int npass = (R + HW - 1) / HW;
      int win = (R + npass - 1) / npass;
      for (int p = 0; p < npass; ++p) {
        FillUnit u = {ds[i], ss[i], iv[i], coff[i], ms[i], (i == 0) ? 1 : 0,
                      Es[i], R, p * win, min((p + 1) * win, R)};
        if (i < 2) big[nbig++] = u; else sml[nsml++] = u;
      }
    }
    int nu = 0, bb = 0, ib = 0, is = 0;
    while (ib < nbig || is < nsml) {
      if (ib < nbig) { F.u[nu] = big[ib++]; F.blkbase[nu] = bb; bb += HNB; ++nu; }
      if (is < nsml) { F.u[nu] = sml[is++]; F.blkbase[nu] = bb; bb += HNB; ++nu; }
    }
    F.nunits = nu;
    F.blkbase[nu] = bb;
    F.nblk = bb;
    F.n8 = (bb + 7) / 8;
    F.wn0 = wnode; F.we0 = wedge;
    fill_k<<<dim3(F.n8 * 8), 1024, 0, stream>>>(F);
  }

  // ---- gathers (multi-job, edge-balanced XCD chunking) ----
  auto launch_bg = [&](GJob* jobs, const int* rows, const long* edges, int nj) {
    GJobs J{};
    int tot = 0;
    long totE = 0;
    for (int k = 0; k < nj; ++k) {
      J.j[k] = jobs[k];
      J.j[k].rbeg = tot;
      tot += rows[k];
      totE += edges[k];
    }
    for (int k = nj; k < 6; ++k) { J.j[k] = J.j[0]; J.j[k].rbeg = 0x7fffffff; }
    J.total = tot;
    int nblk = (tot + 3) / 4;
    J.xbeg[0] = 0;
    for (int x = 1; x < 8; ++x) {
      double target = (double)totE * x / 8.0;
      double cum = 0.0;
      int widbase = 0, wid = tot;
      for (int k = 0; k < nj; ++k) {
        double je = (double)edges[k];
        if (cum + je >= target) {
          double frac = (target - cum) / je;
          wid = widbase + (int)(frac * rows[k]);
          break;
        }
        cum += je;
        widbase += rows[k];
      }
      int vb = wid >> 2;
      if (vb < J.xbeg[x - 1]) vb = J.xbeg[x - 1];
      if (vb > nblk) vb = nblk;
      J.xbeg[x] = vb;
    }
    J.xbeg[8] = nblk;
    int maxspan = 0;
    for (int x = 0; x < 8; ++x) maxspan = max(maxspan, J.xbeg[x + 1] - J.xbeg[x]);
    gather_multi_k<<<dim3(maxspan * 8), 256, 0, stream>>>(J);
  };

  // G1 (same-table jobs adjacent: five ieh-readers first, ueh-reader last)
  {
    GJob js[6] = {
      {ieh, oUGu, mUGu, invU, hu1, nullptr, 0},
      {ieh, oAnd[0], mAnd[0], iAi[0], ab[0], nullptr, 0},
      {ieh, oAnd[1], mAnd[1], iAi[1], ab[1], nullptr, 0},
      {ieh, oAnd[2], mAnd[2], iAi[2], ab[2], nullptr, 0},
      {ieh, oOr, mOr, iOi, ob[0], nullptr, 0},
      {ueh, oUGg, mUGg, invG, hg1, nullptr, 0},
    };
    const int rows[6] = {NU, NI, NI, NI, NI, NI};
    const long edges[6] = {EUG, EAND, EAND, EAND, EOR, EUG};
    launch_bg(js, rows, edges, 6);
  }
  // G2 (6 distinct tables)
  {
    GJob js[6] = {
      {hg1, oUGu, mUGu, invU, nullptr, out_hu, 0},
      {hu1, oUGg, mUGg, invG, hg2, nullptr, 0},
      {ab[0], oAnd[0], mAnd[0], iAi[0], ab[3], nullptr, 0},
      {ab[1], oAnd[1], mAnd[1], iAi[1], ab[4], nullptr, 0},
      {ab[2], oAnd[2], mAnd[2], iAi[2], ab[5], nullptr, 0},
      {ob[0], oOr, mOr, iOi, ob[1], nullptr, 0},
    };
    const int rows[6] = {NU, NI, NI, NI, NI, NI};
    const long edges[6] = {EUG, EUG, EAND, EAND, EAND, EOR};
    launch_bg(js, rows, edges, 6);
  }
  // G3: ob2<-ob1
  {
    GJob js[1] = {{ob[1], oOr, mOr, iOi, ob[2], nullptr, 0}};
    const int rows[1] = {NI};
    const long edges[1] = {EOR};
    launch_bg(js, rows, edges, 1);
  }

  const float w_or = 80.0f / 82.0f;
  const float w_and = w_or / 80.0f;   // = 1/82
  const float w_self = w_and;

  // ---- layer attention ----
  AttnArgs aa{};
  aa.layer[0] = ieh;
  for (int i = 0; i < 6; ++i) aa.layer[1 + i] = ab[i];
  for (int i = 0; i < 7; ++i) aa.coef[i] = 1.0f;
  attn_k<7><<<dim3((NI + 31) / 32, 2), 256, 0, stream>>>(
      aa, W_and, a_and, out_game, w_and, 0, nullptr, 0.f, NI);

  AttnArgs ao{};
  ao.layer[0] = ieh; ao.layer[1] = ob[0]; ao.layer[2] = ob[1]; ao.layer[3] = ob[2];
  ao.coef[0] = 1.0f; ao.coef[1] = 0.6f; ao.coef[2] = 0.8f; ao.coef[3] = 1.0f;
  attn_k<4><<<dim3((NI + 31) / 32, 2), 256, 0, stream>>>(
      ao, W_or, a_or, out_game, w_or, 1, hg2, w_self, NI);
}

// Round 16
// 1173.319 us; speedup vs baseline: 1.1232x; 1.0417x over previous
//
#include <hip/hip_runtime.h>
#include <hip/hip_bf16.h>
#include <math.h>

namespace {

constexpr int NU   = 50000;
constexpr int NI   = 30000;
constexpr int D    = 128;
constexpr int EUG  = 2000000;
constexpr int EAND = 1000000;
constexpr int EOR  = 1000000;
constexpr int HNB  = 32;     // chunks per (array,window) unit
constexpr int HW   = 16000;  // max node window (64 KB LDS)

// ---- bf16 helpers ----
__device__ inline float bf_lo(unsigned v) { union { unsigned u; float f; } x{v << 16}; return x.f; }
__device__ inline float bf_hi(unsigned v) { union { unsigned u; float f; } x{v & 0xffff0000u}; return x.f; }
__device__ inline unsigned short f2bf(float f) {
  union { float f; unsigned u; } x{f};
  unsigned r = x.u + 0x7fffu + ((x.u >> 16) & 1u);
  return (unsigned short)(r >> 16);
}
__device__ inline unsigned pack2bf(float a, float b) {
  return (unsigned)f2bf(a) | ((unsigned)f2bf(b) << 16);
}

// ---------- histograms: per-chunk counts, direct stores (no global atomics) + bf16 cvt ----------
struct HistoUnit { const int* idx; int* cntc; int E; int R; int wbeg; int wend; };
struct HistoAll {
  HistoUnit u[22];
  int blkbase[23];
  int nunits;
  int nhisto;
  const float* a; unsigned* ah; long n2a;
  const float* b; unsigned* bh; long n2b;
};
__global__ __launch_bounds__(1024) void histo_cvt_k(HistoAll H) {
  __shared__ int h[HW];
  int gb = (int)blockIdx.x;
  if (gb >= H.nhisto) {
    long nb = (long)gridDim.x - H.nhisto;
    long total = H.n2a + H.n2b;
    for (long t = (long)(gb - H.nhisto) * 1024 + threadIdx.x; t < total; t += nb * 1024) {
      if (t < H.n2a) {
        float2 v = ((const float2*)H.a)[t];
        H.ah[t] = pack2bf(v.x, v.y);
      } else {
        long u = t - H.n2a;
        float2 v = ((const float2*)H.b)[u];
        H.bh[u] = pack2bf(v.x, v.y);
      }
    }
    return;
  }
  int unit = 0;
#pragma unroll
  for (int i = 1; i < 22; ++i) if (i < H.nunits && gb >= H.blkbase[i]) unit = i;
  HistoUnit U = H.u[unit];
  const int W = U.wend - U.wbeg;
  for (int i = threadIdx.x; i < W; i += 1024) h[i] = 0;
  __syncthreads();
  int chunk = gb - H.blkbase[unit];
  long b = (long)U.E * chunk / HNB;
  long e = (long)U.E * (chunk + 1) / HNB;
  const int* __restrict__ idx = U.idx;
  for (long j = b + threadIdx.x; j < e; j += 1024) {
    int v = idx[j] - U.wbeg;
    if ((unsigned)v < (unsigned)W) atomicAdd(&h[v], 1);
  }
  __syncthreads();
  int* __restrict__ dstc = U.cntc + (size_t)chunk * U.R + U.wbeg;
  for (int i = threadIdx.x; i < W; i += 1024) dstc[i] = h[i];
}

// ---------- per-node totals + norms (coalesced: 1 thread / node) ----------
struct RedAll {
  const int* cb[10];
  int rr[10];
  int nb[11];
  int* cnt_all;
  float* inv_all;
  int ncnt;
};
__global__ __launch_bounds__(256) void reduce_norms_k(RedAll S) {
  int t = (int)blockIdx.x * 256 + (int)threadIdx.x;
  if (t >= S.ncnt) return;
  int a = 0;
#pragma unroll
  for (int i = 1; i < 10; ++i) if (t >= S.nb[i]) a = i;
  int n = t - S.nb[a];
  const int* __restrict__ cb = S.cb[a];
  int R = S.rr[a];
  int sum = 0;
#pragma unroll
  for (int c = 0; c < HNB; ++c) sum += cb[(size_t)c * R + n];
  S.cnt_all[t] = sum;
  S.inv_all[t] = rsqrtf((float)max(sum, 1));
}

// ---------- 6-block exclusive scan over per-node totals ----------
struct ScanSeg { const int* cnt; int* off; int n; };
struct ScanAll { ScanSeg s[6]; };
__global__ __launch_bounds__(1024) void exscan_k(ScanAll S) {
  ScanSeg sg = S.s[blockIdx.x];
  __shared__ int ts[1024];
  const int t = threadIdx.x;
  const int per = (sg.n + 1023) >> 10;
  const int b = min(t * per, sg.n);
  const int e = min(b + per, sg.n);
  int s = 0;
  for (int i = b; i < e; ++i) s += sg.cnt[i];
  ts[t] = s;
  __syncthreads();
  for (int d = 1; d < 1024; d <<= 1) {
    int v = (t >= d) ? ts[t - d] : 0;
    __syncthreads();
    ts[t] += v;
    __syncthreads();
  }
  if (t == 1023) sg.off[sg.n] = ts[1023];
  int run = (t == 0) ? 0 : ts[t - 1];
  for (int i = b; i < e; ++i) { sg.off[i] = run; run += sg.cnt[i]; }
}

// ---------- per-chunk cursor bases (coalesced: 1 thread / node) ----------
struct CoffAll {
  const int* cntc[6];
  const int* off[6];
  int* coff[6];
  int n[6];
  int base[7];
};
__global__ __launch_bounds__(256) void coffs_k(CoffAll S) {
  int t = (int)blockIdx.x * 256 + (int)threadIdx.x;
  if (t >= S.base[6]) return;
  int seg = 0;
#pragma unroll
  for (int i = 1; i < 6; ++i) if (t >= S.base[i]) seg = i;
  int n = t - S.base[seg];
  int R = S.n[seg];
  const int* __restrict__ cc = S.cntc[seg];
  int* __restrict__ co = S.coff[seg];
  int run = S.off[seg][n];
#pragma unroll
  for (int c = 0; c < HNB; ++c) {
    co[(size_t)c * R + n] = run;
    run += cc[(size_t)c * R + n];
  }
}

// ---------- atomic-free CSR fill with XCD-chunked swizzle ----------
struct FillUnit {
  const int* dst; const int* src; const float* invS; const int* coff;
  unsigned* meta; int iswt; int E; int R; int wbeg; int wend;
};
struct FillAll {
  FillUnit u[14];
  int blkbase[15];
  int nunits;
  int nblk;
  int n8;
  const float* wn0;
  const float* we0;
};
__global__ __launch_bounds__(1024) void fill_k(FillAll F) {
  __shared__ int cur[HW];
  int b = (int)blockIdx.x;
  int gb = (b & 7) * F.n8 + (b >> 3);   // XCD-chunked
  if (gb >= F.nblk) return;
  int unit = 0;
#pragma unroll
  for (int i = 1; i < 14; ++i) if (i < F.nunits && gb >= F.blkbase[i]) unit = i;
  FillUnit U = F.u[unit];
  const int W = U.wend - U.wbeg;
  int chunk = gb - F.blkbase[unit];
  const int* __restrict__ coff = U.coff + (size_t)chunk * U.R + U.wbeg;
  for (int i = threadIdx.x; i < W; i += 1024) cur[i] = coff[i];
  __syncthreads();
  long bb = (long)U.E * chunk / HNB;
  long ee = (long)U.E * (chunk + 1) / HNB;
  const int* __restrict__ dst = U.dst;
  const int* __restrict__ src = U.src;
  const float* __restrict__ invS = U.invS;
  for (long j = bb + threadIdx.x; j < ee; j += 1024) {
    int dn = dst[j];
    int v = dn - U.wbeg;
    if ((unsigned)v < (unsigned)W) {
      int sn = src[j];
      float w = invS[sn];
      if (U.iswt) w *= F.wn0[sn] * F.we0[j];
      int pos = atomicAdd(&cur[v], 1);
      U.meta[pos] = ((unsigned)f2bf(w) << 16) | (unsigned)sn;
    }
  }
}

// ---------- multi-job pull aggregation: ROW-PAIR waves ----------
// Each wave owns two adjacent rows: lanes 0-31 -> row 2p, lanes 32-63 -> row 2p+1.
// uint2 row reads (32 lanes = full 256 B row); divergence only between halves;
// no cross-lane ops; pair rows adjacent -> stores fully coalesced.
struct GJob {
  const unsigned* x; const int* roff; const unsigned* meta;
  const float* invD; unsigned* out_h; float* out_f; int rbeg; int nrows;
};
struct GJobs { GJob j[6]; int total; int xbeg[9]; };  // total/rbeg in PAIR units

__global__ __launch_bounds__(256) void gather_multi_k(GJobs J) {
  int b = (int)blockIdx.x;
  int xcd = b & 7;
  int vb = J.xbeg[xcd] + (b >> 3);
  if (vb >= J.xbeg[xcd + 1]) return;
  int wid = (vb << 2) | ((int)threadIdx.x >> 6);   // pair id
  if (wid >= J.total) return;
  GJob jb = J.j[0];
#pragma unroll
  for (int i = 1; i < 6; ++i) if (wid >= J.j[i].rbeg) jb = J.j[i];
  int pr = wid - jb.rbeg;
  int lane = (int)threadIdx.x & 63;
  int hf = lane >> 5;
  int l32 = lane & 31;
  int row = (pr << 1) | hf;
  bool valid = (row < jb.nrows);
  int lo = 0, hi = 0;
  if (valid) { lo = jb.roff[row]; hi = jb.roff[row + 1]; }
  const uint2* __restrict__ x2 = (const uint2*)jb.x;
  const unsigned* __restrict__ mt = jb.meta;
  float a0 = 0.f, a1 = 0.f, a2 = 0.f, a3 = 0.f;

#define PEDGE(m)                                           \
  {                                                        \
    int s = (int)((m) & 0xffffu);                          \
    float w = bf_hi(m);                                    \
    uint2 r = x2[(size_t)s * 32 + l32];                    \
    a0 = fmaf(w, bf_lo(r.x), a0);                          \
    a1 = fmaf(w, bf_hi(r.x), a1);                          \
    a2 = fmaf(w, bf_lo(r.y), a2);                          \
    a3 = fmaf(w, bf_hi(r.y), a3);                          \
  }

  int j = lo;
  for (; j + 3 < hi; j += 4) {
    unsigned m0 = mt[j], m1 = mt[j + 1], m2 = mt[j + 2], m3 = mt[j + 3];
    PEDGE(m0) PEDGE(m1) PEDGE(m2) PEDGE(m3)
  }
  for (; j < hi; ++j) {
    unsigned m = mt[j];
    PEDGE(m)
  }
#undef PEDGE

  if (valid) {
    float si = jb.invD[row];
    a0 *= si; a1 *= si; a2 *= si; a3 *= si;
    if (jb.out_f) {
      ((float4*)jb.out_f)[(size_t)row * 32 + l32] = make_float4(a0, a1, a2, a3);
    } else {
      uint2 o;
      o.x = pack2bf(a0, a1);
      o.y = pack2bf(a2, a3);
      ((uint2*)jb.out_h)[(size_t)row * 32 + l32] = o;
    }
  }
}

// ---------- layer attention (verified since r2; bf16 layers) ----------
struct AttnArgs {
  const unsigned* layer[7];
  float coef[7];
};

__device__ inline void osm_upd(float& m, float& den, float& num, float sc, float tv) {
  float nm = fmaxf(m, sc);
  float e0 = __expf(m - nm);
  float e1 = __expf(sc - nm);
  den = den * e0 + e1;
  num = num * e0 + tv * e1;
  m = nm;
}

template <int L>
__global__ __launch_bounds__(256) void attn_k(AttnArgs args,
    const float* __restrict__ W, const float* __restrict__ avec,
    float* __restrict__ out, float out_scale, int beta,
    const unsigned* __restrict__ extra, float escale, int n) {
  __shared__ float4 Ws4[2048];
  __shared__ float xs[32][132];
  const int tid = threadIdx.x;
  const int dt = tid & 15;
  const int grp = tid >> 4;
  const int half = blockIdx.y;
  const int base = blockIdx.x * 32;
  const float4* __restrict__ W4 = (const float4*)W;

  for (int i = tid; i < 2048; i += 256) {
    int k = i >> 4, d = i & 15;
    Ws4[i] = W4[(k << 5) + (half << 4) + d];
  }
  const float4 a4 = ((const float4*)avec)[(half << 4) + dt];
  const float am[4] = {a4.x, a4.y, a4.z, a4.w};

  float m[2][4], den[2][4], num[2][4];
#pragma unroll
  for (int g = 0; g < 2; ++g)
#pragma unroll
    for (int c = 0; c < 4; ++c) { m[g][c] = -3.0e38f; den[g][c] = 0.f; num[g][c] = 0.f; }

#pragma unroll
  for (int l = 0; l < L; ++l) {
    __syncthreads();
    const unsigned* __restrict__ Lh = args.layer[l];
    for (int i = tid; i < 2048; i += 256) {
      int r = i >> 6, c2 = i & 63;
      int node = base + r;
      unsigned v = (node < n) ? Lh[(size_t)node * 64 + c2] : 0u;
      xs[r][(c2 << 1)] = bf_lo(v);
      xs[r][(c2 << 1) + 1] = bf_hi(v);
    }
    __syncthreads();
    float s0[4] = {0.f, 0.f, 0.f, 0.f}, s1[4] = {0.f, 0.f, 0.f, 0.f};
#pragma unroll 4
    for (int k = 0; k < 128; ++k) {
      float4 w = Ws4[(k << 4) + dt];
      float x0 = xs[grp][k];
      float x1 = xs[grp + 16][k];
      s0[0] = fmaf(x0, w.x, s0[0]); s0[1] = fmaf(x0, w.y, s0[1]);
      s0[2] = fmaf(x0, w.z, s0[2]); s0[3] = fmaf(x0, w.w, s0[3]);
      s1[0] = fmaf(x1, w.x, s1[0]); s1[1] = fmaf(x1, w.y, s1[1]);
      s1[2] = fmaf(x1, w.z, s1[2]); s1[3] = fmaf(x1, w.w, s1[3]);
    }
    float c = args.coef[l];
    float4 t0 = *(const float4*)&xs[grp][(half << 6) + (dt << 2)];
    float4 t1 = *(const float4*)&xs[grp + 16][(half << 6) + (dt << 2)];
    const float tv0[4] = {t0.x, t0.y, t0.z, t0.w};
    const float tv1[4] = {t1.x, t1.y, t1.z, t1.w};
#pragma unroll
    for (int ch = 0; ch < 4; ++ch) {
      osm_upd(m[0][ch], den[0][ch], num[0][ch], c * s0[ch] * am[ch], c * tv0[ch]);
      osm_upd(m[1][ch], den[1][ch], num[1][ch], c * s1[ch] * am[ch], c * tv1[ch]);
    }
  }
#pragma unroll
  for (int g = 0; g < 2; ++g) {
    int node = base + grp + g * 16;
    if (node >= n) continue;
    float4 o;
    o.x = num[g][0] / den[g][0];
    o.y = num[g][1] / den[g][1];
    o.z = num[g][2] / den[g][2];
    o.w = num[g][3] / den[g][3];
    size_t oi = (size_t)node * 32 + (half << 4) + dt;
    float4* op = (float4*)out + oi;
    if (beta) {
      float4 pv = *op;
      float ex = 0.f, ey = 0.f, ez = 0.f, ew = 0.f;
      if (extra) {
        uint2 ev = ((const uint2*)extra)[oi];
        ex = bf_lo(ev.x); ey = bf_hi(ev.x); ez = bf_lo(ev.y); ew = bf_hi(ev.y);
      }
      o.x = pv.x + out_scale * o.x + escale * ex;
      o.y = pv.y + out_scale * o.y + escale * ey;
      o.z = pv.z + out_scale * o.z + escale * ez;
      o.w = pv.w + out_scale * o.w + escale * ew;
    } else {
      o.x *= out_scale; o.y *= out_scale; o.z *= out_scale; o.w *= out_scale;
    }
    *op = o;
  }
}

inline dim3 g1(long n) { return dim3((unsigned)((n + 255) / 256)); }

} // namespace

extern "C" void kernel_launch(void* const* d_in, const int* in_sizes, int n_in,
                              void* d_out, int out_size, void* d_ws, size_t ws_size,
                              hipStream_t stream) {
  const int* ug_u = (const int*)d_in[0];
  const int* ug_g = (const int*)d_in[1];
  const int* aS[3] = {(const int*)d_in[2], (const int*)d_in[4], (const int*)d_in[6]};
  const int* aD[3] = {(const int*)d_in[3], (const int*)d_in[5], (const int*)d_in[7]};
  const int* oS = (const int*)d_in[8];
  const int* oD = (const int*)d_in[9];
  const float* ue    = (const float*)d_in[10];
  const float* ie    = (const float*)d_in[11];
  const float* W_and = (const float*)d_in[12];
  const float* a_and = (const float*)d_in[13];
  const float* W_or  = (const float*)d_in[14];
  const float* a_or  = (const float*)d_in[15];
  const float* wedge = (const float*)d_in[16];
  const float* wnode = (const float*)d_in[17];

  // ---- workspace carve-up ----
  char* basep = (char*)d_ws;
  size_t boff_ = 0;
  auto alloc = [&](size_t bytes) -> void* {
    void* r = basep + boff_;
    boff_ += (bytes + 15) & ~(size_t)15;
    return r;
  };

  const int NCNT = NU + 9 * NI;
  const int RR[10] = {NU, NI, NI, NI, NI, NI, NI, NI, NI, NI};
  int* cntc[10];
  for (int i = 0; i < 10; ++i) cntc[i] = (int*)alloc((size_t)HNB * RR[i] * 4);
  int* cnt_all = (int*)alloc((size_t)NCNT * 4);
  float* inv_all = (float*)alloc((size_t)NCNT * 4);
  float* invU = inv_all;
  float* invG = invU + NU;
  float* iAo[3] = {invG + NI, invG + 3 * NI, invG + 5 * NI};
  float* iAi[3] = {invG + 2 * NI, invG + 4 * NI, invG + 6 * NI};
  float* iOo = invG + 7 * NI;
  float* iOi = invG + 8 * NI;
  int* cU_t = cnt_all;
  int* cG_t = cU_t + NU;
  int* cAd_t[3] = {cG_t + 2 * NI, cG_t + 4 * NI, cG_t + 6 * NI};
  int* cOd_t = cG_t + 8 * NI;

  int* oUGu = (int*)alloc((size_t)(NU + 1) * 4);
  int* oUGg = (int*)alloc((size_t)(NI + 1) * 4);
  int* oAnd[3]; for (int i = 0; i < 3; ++i) oAnd[i] = (int*)alloc((size_t)(NI + 1) * 4);
  int* oOr = (int*)alloc((size_t)(NI + 1) * 4);

  const int SR[6] = {NU, NI, NI, NI, NI, NI};
  int* coff[6];
  for (int i = 0; i < 6; ++i) coff[i] = (int*)alloc((size_t)HNB * SR[i] * 4);

  unsigned* mUGu = (unsigned*)alloc((size_t)EUG * 4 + 256);
  unsigned* mUGg = (unsigned*)alloc((size_t)EUG * 4 + 256);
  unsigned* mAnd[3]; for (int i = 0; i < 3; ++i) mAnd[i] = (unsigned*)alloc((size_t)EAND * 4 + 256);
  unsigned* mOr = (unsigned*)alloc((size_t)EOR * 4 + 256);

  unsigned* ieh = (unsigned*)alloc((size_t)NI * 64 * 4);
  unsigned* ueh = (unsigned*)alloc((size_t)NU * 64 * 4);
  unsigned* hu1 = (unsigned*)alloc((size_t)NU * 64 * 4);
  unsigned* hg1 = (unsigned*)alloc((size_t)NI * 64 * 4);
  unsigned* hg2 = (unsigned*)alloc((size_t)NI * 64 * 4);
  unsigned* ab[6]; for (int i = 0; i < 6; ++i) ab[i] = (unsigned*)alloc((size_t)NI * 64 * 4);
  unsigned* ob[3]; for (int i = 0; i < 3; ++i) ob[i] = (unsigned*)alloc((size_t)NI * 64 * 4);

  float* out_hu = (float*)d_out;
  float* out_game = out_hu + (size_t)NU * D;

  // ---- histograms (per-chunk, no atomics) + bf16 conversion ----
  HistoAll H{};
  {
    const int* idxs[10] = {ug_u, ug_g, aS[0], aD[0], aS[1], aD[1], aS[2], aD[2], oS, oD};
    int nu = 0, bb = 0;
    for (int i = 0; i < 10; ++i) {
      int E = (i < 2) ? EUG : ((i < 8) ? EAND : EOR);
      int R = RR[i];
      int npass = (R + HW - 1) / HW;
      int win = (R + npass - 1) / npass;
      for (int p = 0; p < npass; ++p) {
        H.u[nu] = {idxs[i], cntc[i], E, R, p * win, min((p + 1) * win, R)};
        H.blkbase[nu] = bb;
        bb += HNB;
        ++nu;
      }
    }
    H.nunits = nu;
    H.blkbase[nu] = bb;
    H.nhisto = bb;
    H.a = ie; H.ah = ieh; H.n2a = (long)NI * 64;
    H.b = ue; H.bh = ueh; H.n2b = (long)NU * 64;
    int ncvt = 1024;
    histo_cvt_k<<<dim3(bb + ncvt), 1024, 0, stream>>>(H);
  }

  // ---- per-node totals + norms (coalesced) ----
  RedAll RA{};
  {
    int nbase = 0;
    for (int i = 0; i < 10; ++i) { RA.cb[i] = cntc[i]; RA.rr[i] = RR[i]; RA.nb[i] = nbase; nbase += RR[i]; }
    RA.nb[10] = nbase;
    RA.cnt_all = cnt_all; RA.inv_all = inv_all; RA.ncnt = NCNT;
  }
  reduce_norms_k<<<g1(NCNT), 256, 0, stream>>>(RA);

  // ---- 6-block exclusive scans over totals ----
  ScanAll SA{};
  SA.s[0] = {cU_t, oUGu, NU};
  SA.s[1] = {cG_t, oUGg, NI};
  for (int i = 0; i < 3; ++i) SA.s[2 + i] = {cAd_t[i], oAnd[i], NI};
  SA.s[5] = {cOd_t, oOr, NI};
  exscan_k<<<dim3(6), 1024, 0, stream>>>(SA);

  // ---- per-chunk cursor bases (coalesced) ----
  CoffAll CA{};
  {
    const int segArr[6] = {0, 1, 3, 5, 7, 9};
    const int* offs[6] = {oUGu, oUGg, oAnd[0], oAnd[1], oAnd[2], oOr};
    int base = 0;
    for (int i = 0; i < 6; ++i) {
      CA.cntc[i] = cntc[segArr[i]];
      CA.off[i] = offs[i];
      CA.coff[i] = coff[i];
      CA.n[i] = SR[i];
      CA.base[i] = base; base += SR[i];
    }
    CA.base[6] = base;
    coffs_k<<<g1(base), 256, 0, stream>>>(CA);
  }

  // ---- atomic-free CSR fill (XCD-chunked, big/small interleaved) ----
  FillAll F{};
  {
    const int* ds[6] = {ug_u, ug_g, aD[0], aD[1], aD[2], oD};
    const int* ss[6] = {ug_g, ug_u, aS[0], aS[1], aS[2], oS};
    const float* iv[6] = {invG, invU, iAo[0], iAo[1], iAo[2], iOo};
    unsigned* ms[6] = {mUGu, mUGg, mAnd[0], mAnd[1], mAnd[2], mOr};
    int Es[6] = {EUG, EUG, EAND, EAND, EAND, EOR};
    FillUnit big[8], sml[12];
    int nbig = 0, nsml = 0;
    for (int i = 0; i < 6; ++i) {
      int R = SR[i];
      int npass = (R + HW - 1) / HW;
      int win = (R + npass - 1) / npass;
      for (int p = 0; p < npass; ++p) {
        FillUnit u = {ds[i], ss[i], iv[i], coff[i], ms[i], (i == 0) ? 1 : 0,
                      Es[i], R, p * win, min((p + 1) * win, R)};
        if (i < 2) big[nbig++] = u; else sml[nsml++] = u;
      }
    }
    int nu = 0, bb = 0, ib = 0, is = 0;
    while (ib < nbig || is < nsml) {
      if (ib < nbig) { F.u[nu] = big[ib++]; F.blkbase[nu] = bb; bb += HNB; ++nu; }
      if (is < nsml) { F.u[nu] = sml[is++]; F.blkbase[nu] = bb; bb += HNB; ++nu; }
    }
    F.nunits = nu;
    F.blkbase[nu] = bb;
    F.nblk = bb;
    F.n8 = (bb + 7) / 8;
    F.wn0 = wnode; F.we0 = wedge;
    fill_k<<<dim3(F.n8 * 8), 1024, 0, stream>>>(F);
  }

  // ---- gathers (multi-job, row-pair waves, edge-balanced XCD chunking) ----
  auto launch_bg = [&](GJob* jobs, const int* rows, const long* edges, int nj) {
    GJobs J{};
    int tot = 0;        // pair units
    long totE = 0;
    int pairs[6];
    for (int k = 0; k < nj; ++k) {
      pairs[k] = (rows[k] + 1) / 2;
      J.j[k] = jobs[k];
      J.j[k].rbeg = tot;
      J.j[k].nrows = rows[k];
      tot += pairs[k];
      totE += edges[k];
    }
    for (int k = nj; k < 6; ++k) { J.j[k] = J.j[0]; J.j[k].rbeg = 0x7fffffff; }
    J.total = tot;
    int nblk = (tot + 3) / 4;
    J.xbeg[0] = 0;
    for (int x = 1; x < 8; ++x) {
      double target = (double)totE * x / 8.0;
      double cum = 0.0;
      int pbase = 0, pid = tot;
      for (int k = 0; k < nj; ++k) {
        double je = (double)edges[k];
        if (cum + je >= target) {
          double frac = (target - cum) / je;
          pid = pbase + (int)(frac * pairs[k]);
          break;
        }
        cum += je;
        pbase += pairs[k];
      }
      int vb = pid >> 2;
      if (vb < J.xbeg[x - 1]) vb = J.xbeg[x - 1];
      if (vb > nblk) vb = nblk;
      J.xbeg[x] = vb;
    }
    J.xbeg[8] = nblk;
    int maxspan = 0;
    for (int x = 0; x < 8; ++x) maxspan = max(maxspan, J.xbeg[x + 1] - J.xbeg[x]);
    gather_multi_k<<<dim3(maxspan * 8), 256, 0, stream>>>(J);
  };

  // G1 (same-table jobs adjacent: five ieh-readers first, ueh-reader last)
  {
    GJob js[6] = {
      {ieh, oUGu, mUGu, invU, hu1, nullptr, 0, 0},
      {ieh, oAnd[0], mAnd[0], iAi[0], ab[0], nullptr, 0, 0},
      {ieh, oAnd[1], mAnd[1], iAi[1], ab[1], nullptr, 0, 0},
      {ieh, oAnd[2], mAnd[2], iAi[2], ab[2], nullptr, 0, 0},
      {ieh, oOr, mOr, iOi, ob[0], nullptr, 0, 0},
      {ueh, oUGg, mUGg, invG, hg1, nullptr, 0, 0},
    };
    const int rows[6] = {NU, NI, NI, NI, NI, NI};
    const long edges[6] = {EUG, EAND, EAND, EAND, EOR, EUG};
    launch_bg(js, rows, edges, 6);
  }
  // G2 (6 distinct tables)
  {
    GJob js[6] = {
      {hg1, oUGu, mUGu, invU, nullptr, out_hu, 0, 0},
      {hu1, oUGg, mUGg, invG, hg2, nullptr, 0, 0},
      {ab[0], oAnd[0], mAnd[0], iAi[0], ab[3], nullptr, 0, 0},
      {ab[1], oAnd[1], mAnd[1], iAi[1], ab[4], nullptr, 0, 0},
      {ab[2], oAnd[2], mAnd[2], iAi[2], ab[5], nullptr, 0, 0},
      {ob[0], oOr, mOr, iOi, ob[1], nullptr, 0, 0},
    };
    const int rows[6] = {NU, NI, NI, NI, NI, NI};
    const long edges[6] = {EUG, EUG, EAND, EAND, EAND, EOR};
    launch_bg(js, rows, edges, 6);
  }
  // G3: ob2<-ob1
  {
    GJob js[1] = {{ob[1], oOr, mOr, iOi, ob[2], nullptr, 0, 0}};
    const int rows[1] = {NI};
    const long edges[1] = {EOR};
    launch_bg(js, rows, edges, 1);
  }

  const float w_or = 80.0f / 82.0f;
  const float w_and = w_or / 80.0f;   // = 1/82
  const float w_self = w_and;

  // ---- layer attention ----
  AttnArgs aa{};
  aa.layer[0] = ieh;
  for (int i = 0; i < 6; ++i) aa.layer[1 + i] = ab[i];
  for (int i = 0; i < 7; ++i) aa.coef[i] = 1.0f;
  attn_k<7><<<dim3((NI + 31) / 32, 2), 256, 0, stream>>>(
      aa, W_and, a_and, out_game, w_and, 0, nullptr, 0.f, NI);

  AttnArgs ao{};
  ao.layer[0] = ieh; ao.layer[1] = ob[0]; ao.layer[2] = ob[1]; ao.layer[3] = ob[2];
  ao.coef[0] = 1.0f; ao.coef[1] = 0.6f; ao.coef[2] = 0.8f; ao.coef[3] = 1.0f;
  attn_k<4><<<dim3((NI + 31) / 32, 2), 256, 0, stream>>>(
      ao, W_or, a_or, out_game, w_or, 1, hg2, w_self, NI);
}

// Round 17
// 1166.970 us; speedup vs baseline: 1.1293x; 1.0054x over previous
//
#include <hip/hip_runtime.h>
#include <hip/hip_bf16.h>
#include <math.h>

namespace {

constexpr int NU   = 50000;
constexpr int NI   = 30000;
constexpr int D    = 128;
constexpr int EUG  = 2000000;
constexpr int EAND = 1000000;
constexpr int EOR  = 1000000;
constexpr int HNB  = 32;     // chunks per (array,window) unit
constexpr int HW   = 16000;  // max node window (64 KB LDS)

// ---- bf16 helpers ----
__device__ inline float bf_lo(unsigned v) { union { unsigned u; float f; } x{v << 16}; return x.f; }
__device__ inline float bf_hi(unsigned v) { union { unsigned u; float f; } x{v & 0xffff0000u}; return x.f; }
__device__ inline unsigned short f2bf(float f) {
  union { float f; unsigned u; } x{f};
  unsigned r = x.u + 0x7fffu + ((x.u >> 16) & 1u);
  return (unsigned short)(r >> 16);
}
__device__ inline unsigned pack2bf(float a, float b) {
  return (unsigned)f2bf(a) | ((unsigned)f2bf(b) << 16);
}

// ---------- histograms: per-chunk counts, direct stores (no global atomics) + bf16 cvt ----------
struct HistoUnit { const int* idx; int* cntc; int E; int R; int wbeg; int wend; };
struct HistoAll {
  HistoUnit u[22];
  int blkbase[23];
  int nunits;
  int nhisto;
  const float* a; unsigned* ah; long n2a;
  const float* b; unsigned* bh; long n2b;
};
__global__ __launch_bounds__(1024) void histo_cvt_k(HistoAll H) {
  __shared__ int h[HW];
  int gb = (int)blockIdx.x;
  if (gb >= H.nhisto) {
    long nb = (long)gridDim.x - H.nhisto;
    long total = H.n2a + H.n2b;
    for (long t = (long)(gb - H.nhisto) * 1024 + threadIdx.x; t < total; t += nb * 1024) {
      if (t < H.n2a) {
        float2 v = ((const float2*)H.a)[t];
        H.ah[t] = pack2bf(v.x, v.y);
      } else {
        long u = t - H.n2a;
        float2 v = ((const float2*)H.b)[u];
        H.bh[u] = pack2bf(v.x, v.y);
      }
    }
    return;
  }
  int unit = 0;
#pragma unroll
  for (int i = 1; i < 22; ++i) if (i < H.nunits && gb >= H.blkbase[i]) unit = i;
  HistoUnit U = H.u[unit];
  const int W = U.wend - U.wbeg;
  for (int i = threadIdx.x; i < W; i += 1024) h[i] = 0;
  __syncthreads();
  int chunk = gb - H.blkbase[unit];
  long b = (long)U.E * chunk / HNB;
  long e = (long)U.E * (chunk + 1) / HNB;
  const int* __restrict__ idx = U.idx;
  for (long j = b + threadIdx.x; j < e; j += 1024) {
    int v = idx[j] - U.wbeg;
    if ((unsigned)v < (unsigned)W) atomicAdd(&h[v], 1);
  }
  __syncthreads();
  int* __restrict__ dstc = U.cntc + (size_t)chunk * U.R + U.wbeg;
  for (int i = threadIdx.x; i < W; i += 1024) dstc[i] = h[i];
}

// ---------- per-node totals + norms (coalesced: 1 thread / node) ----------
struct RedAll {
  const int* cb[10];
  int rr[10];
  int nb[11];
  int* cnt_all;
  float* inv_all;
  int ncnt;
};
__global__ __launch_bounds__(256) void reduce_norms_k(RedAll S) {
  int t = (int)blockIdx.x * 256 + (int)threadIdx.x;
  if (t >= S.ncnt) return;
  int a = 0;
#pragma unroll
  for (int i = 1; i < 10; ++i) if (t >= S.nb[i]) a = i;
  int n = t - S.nb[a];
  const int* __restrict__ cb = S.cb[a];
  int R = S.rr[a];
  int sum = 0;
#pragma unroll
  for (int c = 0; c < HNB; ++c) sum += cb[(size_t)c * R + n];
  S.cnt_all[t] = sum;
  S.inv_all[t] = rsqrtf((float)max(sum, 1));
}

// ---------- 6-block exclusive scan over per-node totals ----------
struct ScanSeg { const int* cnt; int* off; int n; };
struct ScanAll { ScanSeg s[6]; };
__global__ __launch_bounds__(1024) void exscan_k(ScanAll S) {
  ScanSeg sg = S.s[blockIdx.x];
  __shared__ int ts[1024];
  const int t = threadIdx.x;
  const int per = (sg.n + 1023) >> 10;
  const int b = min(t * per, sg.n);
  const int e = min(b + per, sg.n);
  int s = 0;
  for (int i = b; i < e; ++i) s += sg.cnt[i];
  ts[t] = s;
  __syncthreads();
  for (int d = 1; d < 1024; d <<= 1) {
    int v = (t >= d) ? ts[t - d] : 0;
    __syncthreads();
    ts[t] += v;
    __syncthreads();
  }
  if (t == 1023) sg.off[sg.n] = ts[1023];
  int run = (t == 0) ? 0 : ts[t - 1];
  for (int i = b; i < e; ++i) { sg.off[i] = run; run += sg.cnt[i]; }
}

// ---------- per-chunk cursor bases (coalesced: 1 thread / node) ----------
struct CoffAll {
  const int* cntc[6];
  const int* off[6];
  int* coff[6];
  int n[6];
  int base[7];
};
__global__ __launch_bounds__(256) void coffs_k(CoffAll S) {
  int t = (int)blockIdx.x * 256 + (int)threadIdx.x;
  if (t >= S.base[6]) return;
  int seg = 0;
#pragma unroll
  for (int i = 1; i < 6; ++i) if (t >= S.base[i]) seg = i;
  int n = t - S.base[seg];
  int R = S.n[seg];
  const int* __restrict__ cc = S.cntc[seg];
  int* __restrict__ co = S.coff[seg];
  int run = S.off[seg][n];
#pragma unroll
  for (int c = 0; c < HNB; ++c) {
    co[(size_t)c * R + n] = run;
    run += cc[(size_t)c * R + n];
  }
}

// ---------- atomic-free CSR fill with XCD-chunked swizzle ----------
struct FillUnit {
  const int* dst; const int* src; const float* invS; const int* coff;
  unsigned* meta; int iswt; int E; int R; int wbeg; int wend;
};
struct FillAll {
  FillUnit u[14];
  int blkbase[15];
  int nunits;
  int nblk;
  int n8;
  const float* wn0;
  const float* we0;
};
__global__ __launch_bounds__(1024) void fill_k(FillAll F) {
  __shared__ int cur[HW];
  int b = (int)blockIdx.x;
  int gb = (b & 7) * F.n8 + (b >> 3);   // XCD-chunked
  if (gb >= F.nblk) return;
  int unit = 0;
#pragma unroll
  for (int i = 1; i < 14; ++i) if (i < F.nunits && gb >= F.blkbase[i]) unit = i;
  FillUnit U = F.u[unit];
  const int W = U.wend - U.wbeg;
  int chunk = gb - F.blkbase[unit];
  const int* __restrict__ coff = U.coff + (size_t)chunk * U.R + U.wbeg;
  for (int i = threadIdx.x; i < W; i += 1024) cur[i] = coff[i];
  __syncthreads();
  long bb = (long)U.E * chunk / HNB;
  long ee = (long)U.E * (chunk + 1) / HNB;
  const int* __restrict__ dst = U.dst;
  const int* __restrict__ src = U.src;
  const float* __restrict__ invS = U.invS;
  for (long j = bb + threadIdx.x; j < ee; j += 1024) {
    int dn = dst[j];
    int v = dn - U.wbeg;
    if ((unsigned)v < (unsigned)W) {
      int sn = src[j];
      float w = invS[sn];
      if (U.iswt) w *= F.wn0[sn] * F.we0[j];
      int pos = atomicAdd(&cur[v], 1);
      U.meta[pos] = ((unsigned)f2bf(w) << 16) | (unsigned)sn;
    }
  }
}

// ---------- multi-job pull aggregation: ROW-PAIR waves, 8-deep unroll ----------
// Each wave owns two adjacent rows: lanes 0-31 -> row 2p, lanes 32-63 -> row 2p+1.
// uint2 row reads (32 lanes = full 256 B row); no cross-lane ops; coalesced stores.
struct GJob {
  const unsigned* x; const int* roff; const unsigned* meta;
  const float* invD; unsigned* out_h; float* out_f; int rbeg; int nrows;
};
struct GJobs { GJob j[6]; int total; int xbeg[9]; };  // total/rbeg in PAIR units

__global__ __launch_bounds__(256) void gather_multi_k(GJobs J) {
  int b = (int)blockIdx.x;
  int xcd = b & 7;
  int vb = J.xbeg[xcd] + (b >> 3);
  if (vb >= J.xbeg[xcd + 1]) return;
  int wid = (vb << 2) | ((int)threadIdx.x >> 6);   // pair id
  if (wid >= J.total) return;
  GJob jb = J.j[0];
#pragma unroll
  for (int i = 1; i < 6; ++i) if (wid >= J.j[i].rbeg) jb = J.j[i];
  int pr = wid - jb.rbeg;
  int lane = (int)threadIdx.x & 63;
  int hf = lane >> 5;
  int l32 = lane & 31;
  int row = (pr << 1) | hf;
  bool valid = (row < jb.nrows);
  int lo = 0, hi = 0;
  if (valid) { lo = jb.roff[row]; hi = jb.roff[row + 1]; }
  const uint2* __restrict__ x2 = (const uint2*)jb.x;
  const unsigned* __restrict__ mt = jb.meta;
  float a0 = 0.f, a1 = 0.f, a2 = 0.f, a3 = 0.f;

#define PEDGE(m)                                           \
  {                                                        \
    int s = (int)((m) & 0xffffu);                          \
    float w = bf_hi(m);                                    \
    uint2 r = x2[(size_t)s * 32 + l32];                    \
    a0 = fmaf(w, bf_lo(r.x), a0);                          \
    a1 = fmaf(w, bf_hi(r.x), a1);                          \
    a2 = fmaf(w, bf_lo(r.y), a2);                          \
    a3 = fmaf(w, bf_hi(r.y), a3);                          \
  }

  int j = lo;
  for (; j + 7 < hi; j += 8) {
    unsigned mm[8];
#pragma unroll
    for (int k = 0; k < 8; ++k) mm[k] = mt[j + k];
#pragma unroll
    for (int k = 0; k < 8; ++k) PEDGE(mm[k])
  }
  for (; j + 3 < hi; j += 4) {
    unsigned m0 = mt[j], m1 = mt[j + 1], m2 = mt[j + 2], m3 = mt[j + 3];
    PEDGE(m0) PEDGE(m1) PEDGE(m2) PEDGE(m3)
  }
  for (; j < hi; ++j) {
    unsigned m = mt[j];
    PEDGE(m)
  }
#undef PEDGE

  if (valid) {
    float si = jb.invD[row];
    a0 *= si; a1 *= si; a2 *= si; a3 *= si;
    if (jb.out_f) {
      ((float4*)jb.out_f)[(size_t)row * 32 + l32] = make_float4(a0, a1, a2, a3);
    } else {
      uint2 o;
      o.x = pack2bf(a0, a1);
      o.y = pack2bf(a2, a3);
      ((uint2*)jb.out_h)[(size_t)row * 32 + l32] = o;
    }
  }
}

// ---------- layer attention (verified since r2; bf16 layers) ----------
struct AttnArgs {
  const unsigned* layer[7];
  float coef[7];
};

__device__ inline void osm_upd(float& m, float& den, float& num, float sc, float tv) {
  float nm = fmaxf(m, sc);
  float e0 = __expf(m - nm);
  float e1 = __expf(sc - nm);
  den = den * e0 + e1;
  num = num * e0 + tv * e1;
  m = nm;
}

template <int L>
__global__ __launch_bounds__(256) void attn_k(AttnArgs args,
    const float* __restrict__ W, const float* __restrict__ avec,
    float* __restrict__ out, float out_scale, int beta,
    const unsigned* __restrict__ extra, float escale, int n) {
  __shared__ float4 Ws4[2048];
  __shared__ float xs[32][132];
  const int tid = threadIdx.x;
  const int dt = tid & 15;
  const int grp = tid >> 4;
  const int half = blockIdx.y;
  const int base = blockIdx.x * 32;
  const float4* __restrict__ W4 = (const float4*)W;

  for (int i = tid; i < 2048; i += 256) {
    int k = i >> 4, d = i & 15;
    Ws4[i] = W4[(k << 5) + (half << 4) + d];
  }
  const float4 a4 = ((const float4*)avec)[(half << 4) + dt];
  const float am[4] = {a4.x, a4.y, a4.z, a4.w};

  float m[2][4], den[2][4], num[2][4];
#pragma unroll
  for (int g = 0; g < 2; ++g)
#pragma unroll
    for (int c = 0; c < 4; ++c) { m[g][c] = -3.0e38f; den[g][c] = 0.f; num[g][c] = 0.f; }

#pragma unroll
  for (int l = 0; l < L; ++l) {
    __syncthreads();
    const unsigned* __restrict__ Lh = args.layer[l];
    for (int i = tid; i < 2048; i += 256) {
      int r = i >> 6, c2 = i & 63;
      int node = base + r;
      unsigned v = (node < n) ? Lh[(size_t)node * 64 + c2] : 0u;
      xs[r][(c2 << 1)] = bf_lo(v);
      xs[r][(c2 << 1) + 1] = bf_hi(v);
    }
    __syncthreads();
    float s0[4] = {0.f, 0.f, 0.f, 0.f}, s1[4] = {0.f, 0.f, 0.f, 0.f};
#pragma unroll 4
    for (int k = 0; k < 128; ++k) {
      float4 w = Ws4[(k << 4) + dt];
      float x0 = xs[grp][k];
      float x1 = xs[grp + 16][k];
      s0[0] = fmaf(x0, w.x, s0[0]); s0[1] = fmaf(x0, w.y, s0[1]);
      s0[2] = fmaf(x0, w.z, s0[2]); s0[3] = fmaf(x0, w.w, s0[3]);
      s1[0] = fmaf(x1, w.x, s1[0]); s1[1] = fmaf(x1, w.y, s1[1]);
      s1[2] = fmaf(x1, w.z, s1[2]); s1[3] = fmaf(x1, w.w, s1[3]);
    }
    float c = args.coef[l];
    float4 t0 = *(const float4*)&xs[grp][(half << 6) + (dt << 2)];
    float4 t1 = *(const float4*)&xs[grp + 16][(half << 6) + (dt << 2)];
    const float tv0[4] = {t0.x, t0.y, t0.z, t0.w};
    const float tv1[4] = {t1.x, t1.y, t1.z, t1.w};
#pragma unroll
    for (int ch = 0; ch < 4; ++ch) {
      osm_upd(m[0][ch], den[0][ch], num[0][ch], c * s0[ch] * am[ch], c * tv0[ch]);
      osm_upd(m[1][ch], den[1][ch], num[1][ch], c * s1[ch] * am[ch], c * tv1[ch]);
    }
  }
#pragma unroll
  for (int g = 0; g < 2; ++g) {
    int node = base + grp + g * 16;
    if (node >= n) continue;
    float4 o;
    o.x = num[g][0] / den[g][0];
    o.y = num[g][1] / den[g][1];
    o.z = num[g][2] / den[g][2];
    o.w = num[g][3] / den[g][3];
    size_t oi = (size_t)node * 32 + (half << 4) + dt;
    float4* op = (float4*)out + oi;
    if (beta) {
      float4 pv = *op;
      float ex = 0.f, ey = 0.f, ez = 0.f, ew = 0.f;
      if (extra) {
        uint2 ev = ((const uint2*)extra)[oi];
        ex = bf_lo(ev.x); ey = bf_hi(ev.x); ez = bf_lo(ev.y); ew = bf_hi(ev.y);
      }
      o.x = pv.x + out_scale * o.x + escale * ex;
      o.y = pv.y + out_scale * o.y + escale * ey;
      o.z = pv.z + out_scale * o.z + escale * ez;
      o.w = pv.w + out_scale * o.w + escale * ew;
    } else {
      o.x *= out_scale; o.y *= out_scale; o.z *= out_scale; o.w *= out_scale;
    }
    *op = o;
  }
}

inline dim3 g1(long n) { return dim3((unsigned)((n + 255) / 256)); }

} // namespace

extern "C" void kernel_launch(void* const* d_in, const int* in_sizes, int n_in,
                              void* d_out, int out_size, void* d_ws, size_t ws_size,
                              hipStream_t stream) {
  const int* ug_u = (const int*)d_in[0];
  const int* ug_g = (const int*)d_in[1];
  const int* aS[3] = {(const int*)d_in[2], (const int*)d_in[4], (const int*)d_in[6]};
  const int* aD[3] = {(const int*)d_in[3], (const int*)d_in[5], (const int*)d_in[7]};
  const int* oS = (const int*)d_in[8];
  const int* oD = (const int*)d_in[9];
  const float* ue    = (const float*)d_in[10];
  const float* ie    = (const float*)d_in[11];
  const float* W_and = (const float*)d_in[12];
  const float* a_and = (const float*)d_in[13];
  const float* W_or  = (const float*)d_in[14];
  const float* a_or  = (const float*)d_in[15];
  const float* wedge = (const float*)d_in[16];
  const float* wnode = (const float*)d_in[17];

  // ---- workspace carve-up ----
  char* basep = (char*)d_ws;
  size_t boff_ = 0;
  auto alloc = [&](size_t bytes) -> void* {
    void* r = basep + boff_;
    boff_ += (bytes + 15) & ~(size_t)15;
    return r;
  };

  const int NCNT = NU + 9 * NI;
  const int RR[10] = {NU, NI, NI, NI, NI, NI, NI, NI, NI, NI};
  int* cntc[10];
  for (int i = 0; i < 10; ++i) cntc[i] = (int*)alloc((size_t)HNB * RR[i] * 4);
  int* cnt_all = (int*)alloc((size_t)NCNT * 4);
  float* inv_all = (float*)alloc((size_t)NCNT * 4);
  float* invU = inv_all;
  float* invG = invU + NU;
  float* iAo[3] = {invG + NI, invG + 3 * NI, invG + 5 * NI};
  float* iAi[3] = {invG + 2 * NI, invG + 4 * NI, invG + 6 * NI};
  float* iOo = invG + 7 * NI;
  float* iOi = invG + 8 * NI;
  int* cU_t = cnt_all;
  int* cG_t = cU_t + NU;
  int* cAd_t[3] = {cG_t + 2 * NI, cG_t + 4 * NI, cG_t + 6 * NI};
  int* cOd_t = cG_t + 8 * NI;

  int* oUGu = (int*)alloc((size_t)(NU + 1) * 4);
  int* oUGg = (int*)alloc((size_t)(NI + 1) * 4);
  int* oAnd[3]; for (int i = 0; i < 3; ++i) oAnd[i] = (int*)alloc((size_t)(NI + 1) * 4);
  int* oOr = (int*)alloc((size_t)(NI + 1) * 4);

  const int SR[6] = {NU, NI, NI, NI, NI, NI};
  int* coff[6];
  for (int i = 0; i < 6; ++i) coff[i] = (int*)alloc((size_t)HNB * SR[i] * 4);

  unsigned* mUGu = (unsigned*)alloc((size_t)EUG * 4 + 256);
  unsigned* mUGg = (unsigned*)alloc((size_t)EUG * 4 + 256);
  unsigned* mAnd[3]; for (int i = 0; i < 3; ++i) mAnd[i] = (unsigned*)alloc((size_t)EAND * 4 + 256);
  unsigned* mOr = (unsigned*)alloc((size_t)EOR * 4 + 256);

  unsigned* ieh = (unsigned*)alloc((size_t)NI * 64 * 4);
  unsigned* ueh = (unsigned*)alloc((size_t)NU * 64 * 4);
  unsigned* hu1 = (unsigned*)alloc((size_t)NU * 64 * 4);
  unsigned* hg1 = (unsigned*)alloc((size_t)NI * 64 * 4);
  unsigned* hg2 = (unsigned*)alloc((size_t)NI * 64 * 4);
  unsigned* ab[6]; for (int i = 0; i < 6; ++i) ab[i] = (unsigned*)alloc((size_t)NI * 64 * 4);
  unsigned* ob[3]; for (int i = 0; i < 3; ++i) ob[i] = (unsigned*)alloc((size_t)NI * 64 * 4);

  float* out_hu = (float*)d_out;
  float* out_game = out_hu + (size_t)NU * D;

  // ---- histograms (per-chunk, no atomics) + bf16 conversion ----
  HistoAll H{};
  {
    const int* idxs[10] = {ug_u, ug_g, aS[0], aD[0], aS[1], aD[1], aS[2], aD[2], oS, oD};
    int nu = 0, bb = 0;
    for (int i = 0; i < 10; ++i) {
      int E = (i < 2) ? EUG : ((i < 8) ? EAND : EOR);
      int R = RR[i];
      int npass = (R + HW - 1) / HW;
      int win = (R + npass - 1) / npass;
      for (int p = 0; p < npass; ++p) {
        H.u[nu] = {idxs[i], cntc[i], E, R, p * win, min((p + 1) * win, R)};
        H.blkbase[nu] = bb;
        bb += HNB;
        ++nu;
      }
    }
    H.nunits = nu;
    H.blkbase[nu] = bb;
    H.nhisto = bb;
    H.a = ie; H.ah = ieh; H.n2a = (long)NI * 64;
    H.b = ue; H.bh = ueh; H.n2b = (long)NU * 64;
    int ncvt = 1024;
    histo_cvt_k<<<dim3(bb + ncvt), 1024, 0, stream>>>(H);
  }

  // ---- per-node totals + norms (coalesced) ----
  RedAll RA{};
  {
    int nbase = 0;
    for (int i = 0; i < 10; ++i) { RA.cb[i] = cntc[i]; RA.rr[i] = RR[i]; RA.nb[i] = nbase; nbase += RR[i]; }
    RA.nb[10] = nbase;
    RA.cnt_all = cnt_all; RA.inv_all = inv_all; RA.ncnt = NCNT;
  }
  reduce_norms_k<<<g1(NCNT), 256, 0, stream>>>(RA);

  // ---- 6-block exclusive scans over totals ----
  ScanAll SA{};
  SA.s[0] = {cU_t, oUGu, NU};
  SA.s[1] = {cG_t, oUGg, NI};
  for (int i = 0; i < 3; ++i) SA.s[2 + i] = {cAd_t[i], oAnd[i], NI};
  SA.s[5] = {cOd_t, oOr, NI};
  exscan_k<<<dim3(6), 1024, 0, stream>>>(SA);

  // ---- per-chunk cursor bases (coalesced) ----
  CoffAll CA{};
  {
    const int segArr[6] = {0, 1, 3, 5, 7, 9};
    const int* offs[6] = {oUGu, oUGg, oAnd[0], oAnd[1], oAnd[2], oOr};
    int base = 0;
    for (int i = 0; i < 6; ++i) {
      CA.cntc[i] = cntc[segArr[i]];
      CA.off[i] = offs[i];
      CA.coff[i] = coff[i];
      CA.n[i] = SR[i];
      CA.base[i] = base; base += SR[i];
    }
    CA.base[6] = base;
    coffs_k<<<g1(base), 256, 0, stream>>>(CA);
  }

  // ---- atomic-free CSR fill (XCD-chunked, big/small interleaved) ----
  FillAll F{};
  {
    const int* ds[6] = {ug_u, ug_g, aD[0], aD[1], aD[2], oD};
    const int* ss[6] = {ug_g, ug_u, aS[0], aS[1], aS[2], oS};
    const float* iv[6] = {invG, invU, iAo[0], iAo[1], iAo[2], iOo};
    unsigned* ms[6] = {mUGu, mUGg, mAnd[0], mAnd[1], mAnd[2], mOr};
    int Es[6] = {EUG, EUG, EAND, EAND, EAND, EOR};
    FillUnit big[8], sml[12];
    int nbig = 0, nsml = 0;
    for (int i = 0; i < 6; ++i) {
      int R = SR[i];
      int npass = (R + HW - 1) / HW;
      int win = (R + npass - 1) / npass;
      for (int p = 0; p < npass; ++p) {
        FillUnit u = {ds[i], ss[i], iv[i], coff[i], ms[i], (i == 0) ? 1 : 0,
                      Es[i], R, p * win, min((p + 1) * win, R)};
        if (i < 2) big[nbig++] = u; else sml[nsml++] = u;
      }
    }
    int nu = 0, bb = 0, ib = 0, is = 0;
    while (ib < nbig || is < nsml) {
      if (ib < nbig) { F.u[nu] = big[ib++]; F.blkbase[nu] = bb; bb += HNB; ++nu; }
      if (is < nsml) { F.u[nu] = sml[is++]; F.blkbase[nu] = bb; bb += HNB; ++nu; }
    }
    F.nunits = nu;
    F.blkbase[nu] = bb;
    F.nblk = bb;
    F.n8 = (bb + 7) / 8;
    F.wn0 = wnode; F.we0 = wedge;
    fill_k<<<dim3(F.n8 * 8), 1024, 0, stream>>>(F);
  }

  // ---- gathers (multi-job, row-pair waves, edge-balanced XCD chunking) ----
  auto launch_bg = [&](GJob* jobs, const int* rows, const long* edges, int nj) {
    GJobs J{};
    int tot = 0;        // pair units
    long totE = 0;
    int pairs[6];
    for (int k = 0; k < nj; ++k) {
      pairs[k] = (rows[k] + 1) / 2;
      J.j[k] = jobs[k];
      J.j[k].rbeg = tot;
      J.j[k].nrows = rows[k];
      tot += pairs[k];
      totE += edges[k];
    }
    for (int k = nj; k < 6; ++k) { J.j[k] = J.j[0]; J.j[k].rbeg = 0x7fffffff; }
    J.total = tot;
    int nblk = (tot + 3) / 4;
    J.xbeg[0] = 0;
    for (int x = 1; x < 8; ++x) {
      double target = (double)totE * x / 8.0;
      double cum = 0.0;
      int pbase = 0, pid = tot;
      for (int k = 0; k < nj; ++k) {
        double je = (double)edges[k];
        if (cum + je >= target) {
          double frac = (target - cum) / je;
          pid = pbase + (int)(frac * pairs[k]);
          break;
        }
        cum += je;
        pbase += pairs[k];
      }
      int vb = pid >> 2;
      if (vb < J.xbeg[x - 1]) vb = J.xbeg[x - 1];
      if (vb > nblk) vb = nblk;
      J.xbeg[x] = vb;
    }
    J.xbeg[8] = nblk;
    int maxspan = 0;
    for (int x = 0; x < 8; ++x) maxspan = max(maxspan, J.xbeg[x + 1] - J.xbeg[x]);
    gather_multi_k<<<dim3(maxspan * 8), 256, 0, stream>>>(J);
  };

  // G1 (same-table jobs adjacent: five ieh-readers first, ueh-reader last)
  {
    GJob js[6] = {
      {ieh, oUGu, mUGu, invU, hu1, nullptr, 0, 0},
      {ieh, oAnd[0], mAnd[0], iAi[0], ab[0], nullptr, 0, 0},
      {ieh, oAnd[1], mAnd[1], iAi[1], ab[1], nullptr, 0, 0},
      {ieh, oAnd[2], mAnd[2], iAi[2], ab[2], nullptr, 0, 0},
      {ieh, oOr, mOr, iOi, ob[0], nullptr, 0, 0},
      {ueh, oUGg, mUGg, invG, hg1, nullptr, 0, 0},
    };
    const int rows[6] = {NU, NI, NI, NI, NI, NI};
    const long edges[6] = {EUG, EAND, EAND, EAND, EOR, EUG};
    launch_bg(js, rows, edges, 6);
  }
  // G2 (6 distinct tables)
  {
    GJob js[6] = {
      {hg1, oUGu, mUGu, invU, nullptr, out_hu, 0, 0},
      {hu1, oUGg, mUGg, invG, hg2, nullptr, 0, 0},
      {ab[0], oAnd[0], mAnd[0], iAi[0], ab[3], nullptr, 0, 0},
      {ab[1], oAnd[1], mAnd[1], iAi[1], ab[4], nullptr, 0, 0},
      {ab[2], oAnd[2], mAnd[2], iAi[2], ab[5], nullptr, 0, 0},
      {ob[0], oOr, mOr, iOi, ob[1], nullptr, 0, 0},
    };
    const int rows[6] = {NU, NI, NI, NI, NI, NI};
    const long edges[6] = {EUG, EUG, EAND, EAND, EAND, EOR};
    launch_bg(js, rows, edges, 6);
  }
  // G3: ob2<-ob1
  {
    GJob js[1] = {{ob[1], oOr, mOr, iOi, ob[2], nullptr, 0, 0}};
    const int rows[1] = {NI};
    const long edges[1] = {EOR};
    launch_bg(js, rows, edges, 1);
  }

  const float w_or = 80.0f / 82.0f;
  const float w_and = w_or / 80.0f;   // = 1/82
  const float w_self = w_and;

  // ---- layer attention ----
  AttnArgs aa{};
  aa.layer[0] = ieh;
  for (int i = 0; i < 6; ++i) aa.layer[1 + i] = ab[i];
  for (int i = 0; i < 7; ++i) aa.coef[i] = 1.0f;
  attn_k<7><<<dim3((NI + 31) / 32, 2), 256, 0, stream>>>(
      aa, W_and, a_and, out_game, w_and, 0, nullptr, 0.f, NI);

  AttnArgs ao{};
  ao.layer[0] = ieh; ao.layer[1] = ob[0]; ao.layer[2] = ob[1]; ao.layer[3] = ob[2];
  ao.coef[0] = 1.0f; ao.coef[1] = 0.6f; ao.coef[2] = 0.8f; ao.coef[3] = 1.0f;
  attn_k<4><<<dim3((NI + 31) / 32, 2), 256, 0, stream>>>(
      ao, W_or, a_or, out_game, w_or, 1, hg2, w_self, NI);
}